// Round 4
// baseline (1734.754 us; speedup 1.0000x reference)
//
#include <hip/hip_runtime.h>
#include <math.h>

#define NS 1024
#define DM 512
#define NH 8
#define DEPTH 64

// ws offsets (floats). ctx partials alias qh/kh (dead after k_sumexp).
#define OFF_QH   0
#define OFF_KH   2097152
#define OFF_VH   4194304
#define OFF_CTX0 0
#define OFF_CTX1 2097152
#define OFF_PART 6291456

// swizzles (2-way bank access proven for the respective lane patterns)
#define SW3(row, col) ((col) ^ ((((row) >> 3) & 3) << 3))   // rows 0..31 scatter
#define ESW(row, col) ((col) ^ ((((row) >> 3) & 7) << 2))   // rows 0..63 scatter

// ---------------- QKV projection: X(4096x512)@W(512x512)+b -> split heads
// 128(M)x64(N) tile, BK=32, 8x4/thread, double-buffered LDS. grid (8,32,3)=768
__global__ __launch_bounds__(256, 3) void k_proj(
    const float* __restrict__ q, const float* __restrict__ k, const float* __restrict__ v,
    const float* __restrict__ wq, const float* __restrict__ bq,
    const float* __restrict__ wk, const float* __restrict__ bk,
    const float* __restrict__ wv, const float* __restrict__ bv,
    float* __restrict__ ws)
{
    const float *X, *W, *bias; float* out;
    if (blockIdx.z == 0)      { X=q; W=wq; bias=bq; out=ws+OFF_QH; }
    else if (blockIdx.z == 1) { X=k; W=wk; bias=bk; out=ws+OFF_KH; }
    else                      { X=v; W=wv; bias=bv; out=ws+OFF_VH; }

    __shared__ float As[2][32][132];   // [buf][k][m]
    __shared__ float Bs[2][32][68];    // [buf][k][n]
    const int tid = threadIdx.x, tx = tid & 15, ty = tid >> 4;
    const int n0 = blockIdx.x * 64, m0 = blockIdx.y * 128;
    const int am = tid >> 3, ac4 = tid & 7;        // A staging: col m base, k-group
    const int br_ = tid >> 4, bc4 = tid & 15;      // B staging

    float4 ar[4], brg[2];
    #define LOADP(t) { \
        const int kk = (t)*32; \
        _Pragma("unroll") \
        for (int l = 0; l < 4; ++l) \
            ar[l] = *(const float4*)(X + (size_t)(m0 + am + l*32)*DM + kk + ac4*4); \
        _Pragma("unroll") \
        for (int l = 0; l < 2; ++l) \
            brg[l] = *(const float4*)(W + (size_t)(kk + br_ + l*16)*DM + n0 + bc4*4); \
    }
    #define STOREP(bf) { \
        _Pragma("unroll") \
        for (int l = 0; l < 4; ++l) { \
            const int m = am + l*32; \
            As[bf][ac4*4+0][SW3(ac4*4+0, m)] = ar[l].x; \
            As[bf][ac4*4+1][SW3(ac4*4+1, m)] = ar[l].y; \
            As[bf][ac4*4+2][SW3(ac4*4+2, m)] = ar[l].z; \
            As[bf][ac4*4+3][SW3(ac4*4+3, m)] = ar[l].w; \
        } \
        _Pragma("unroll") \
        for (int l = 0; l < 2; ++l) \
            *(float4*)&Bs[bf][br_ + l*16][bc4*4] = brg[l]; \
    }

    float acc[8][4] = {};
    LOADP(0); STOREP(0);
    for (int t = 0; t < 16; ++t) {
        __syncthreads();
        if (t < 15) LOADP(t+1);
        const int bf = t & 1;
        #pragma unroll
        for (int kq = 0; kq < 32; ++kq) {
            const float4 a0 = *(const float4*)&As[bf][kq][SW3(kq, ty*4)];
            const float4 a1 = *(const float4*)&As[bf][kq][SW3(kq, 64 + ty*4)];
            const float4 b0 = *(const float4*)&Bs[bf][kq][tx*4];
            const float av[8] = {a0.x,a0.y,a0.z,a0.w,a1.x,a1.y,a1.z,a1.w};
            const float bw[4] = {b0.x,b0.y,b0.z,b0.w};
            #pragma unroll
            for (int i = 0; i < 8; ++i)
                #pragma unroll
                for (int j = 0; j < 4; ++j)
                    acc[i][j] = fmaf(av[i], bw[j], acc[i][j]);
        }
        if (t < 15) STOREP(bf ^ 1);
    }
    const int h = n0 >> 6;
    const float4 b4 = *(const float4*)(bias + n0 + tx*4);
    #pragma unroll
    for (int i = 0; i < 8; ++i) {
        const int m = m0 + (i>>2)*64 + ty*4 + (i&3);
        const int bb = m >> 10, s = m & 1023;
        float4 o;
        o.x = acc[i][0]+b4.x; o.y = acc[i][1]+b4.y;
        o.z = acc[i][2]+b4.z; o.w = acc[i][3]+b4.w;
        *(float4*)(out + (((size_t)(bb*NH + h))*NS + s)*DEPTH + tx*4) = o;
    }
    #undef LOADP
    #undef STOREP
}

// ---------------- S = K.Q^T (128x128 tile), e = exp(logits) -> write e + partial sums
__global__ __launch_bounds__(256, 4) void k_sumexp(
    float* __restrict__ ws,
    const float* __restrict__ t_hb, const float* __restrict__ t_pi,
    const float* __restrict__ mask,
    const float* __restrict__ aug_hb, const float* __restrict__ aug_pi,
    const float* __restrict__ aug_at, const int* __restrict__ bnum,
    float* __restrict__ attn)
{
    __shared__ float Ks[32][132];   // [d][i]
    __shared__ float Qs[32][132];   // [d][j]
    __shared__ float wred[4];
    const int bh = blockIdx.z, b = bh >> 3;
    const int i0 = blockIdx.y * 128, j0 = blockIdx.x * 128;
    const float* kh = ws + OFF_KH + (size_t)bh*NS*DEPTH;
    const float* qh = ws + OFF_QH + (size_t)bh*NS*DEPTH;
    const int tid = threadIdx.x, tx = tid & 15, ty = tid >> 4;
    const int ar_ = tid >> 3, ac4 = tid & 7;

    float acc[8][8] = {};
    for (int d0 = 0; d0 < DEPTH; d0 += 32) {
        #pragma unroll
        for (int l = 0; l < 4; ++l) {
            const int r = ar_ + l*32;
            const float4 fk = *(const float4*)(kh + (size_t)(i0+r)*DEPTH + d0 + ac4*4);
            Ks[ac4*4+0][SW3(ac4*4+0, r)]=fk.x; Ks[ac4*4+1][SW3(ac4*4+1, r)]=fk.y;
            Ks[ac4*4+2][SW3(ac4*4+2, r)]=fk.z; Ks[ac4*4+3][SW3(ac4*4+3, r)]=fk.w;
            const float4 fq = *(const float4*)(qh + (size_t)(j0+r)*DEPTH + d0 + ac4*4);
            Qs[ac4*4+0][SW3(ac4*4+0, r)]=fq.x; Qs[ac4*4+1][SW3(ac4*4+1, r)]=fq.y;
            Qs[ac4*4+2][SW3(ac4*4+2, r)]=fq.z; Qs[ac4*4+3][SW3(ac4*4+3, r)]=fq.w;
        }
        __syncthreads();
        #pragma unroll
        for (int d = 0; d < 32; ++d) {
            const float4 a0 = *(const float4*)&Ks[d][SW3(d, ty*4)];
            const float4 a1 = *(const float4*)&Ks[d][SW3(d, 64+ty*4)];
            const float4 b0 = *(const float4*)&Qs[d][SW3(d, tx*4)];
            const float4 b1 = *(const float4*)&Qs[d][SW3(d, 64+tx*4)];
            const float av[8] = {a0.x,a0.y,a0.z,a0.w,a1.x,a1.y,a1.z,a1.w};
            const float bw[8] = {b0.x,b0.y,b0.z,b0.w,b1.x,b1.y,b1.z,b1.w};
            #pragma unroll
            for (int i = 0; i < 8; ++i)
                #pragma unroll
                for (int j = 0; j < 8; ++j)
                    acc[i][j] = fmaf(av[i], bw[j], acc[i][j]);
        }
        __syncthreads();
    }

    const int bn = bnum[0];
    const float at = aug_at[bn], hb = aug_hb[bn], pi = aug_pi[bn];
    const float sc_at = 0.125f*at, m_at = -1e9f*at;
    float local = 0.f;
    #pragma unroll
    for (int i = 0; i < 8; ++i) {
        const int gi = i0 + (i>>2)*64 + ty*4 + (i&3);
        const size_t mrow = ((size_t)b*NS + gi)*NS;
        const size_t trow = (size_t)gi*NS;
        const size_t arow = ((size_t)bh*NS + gi)*NS;
        #pragma unroll
        for (int cb = 0; cb < 2; ++cb) {
            const int gj = j0 + cb*64 + tx*4;
            const float4 m4 = *(const float4*)(mask + mrow + gj);
            const float4 h4 = *(const float4*)(t_hb + trow + gj);
            const float4 p4 = *(const float4*)(t_pi + trow + gj);
            float4 e4;
            e4.x = __expf(fmaf(acc[i][cb*4+0], sc_at, fmaf(m4.x, m_at, fmaf(hb, h4.x, pi*p4.x))));
            e4.y = __expf(fmaf(acc[i][cb*4+1], sc_at, fmaf(m4.y, m_at, fmaf(hb, h4.y, pi*p4.y))));
            e4.z = __expf(fmaf(acc[i][cb*4+2], sc_at, fmaf(m4.z, m_at, fmaf(hb, h4.z, pi*p4.z))));
            e4.w = __expf(fmaf(acc[i][cb*4+3], sc_at, fmaf(m4.w, m_at, fmaf(hb, h4.w, pi*p4.w))));
            *(float4*)(attn + arow + gj) = e4;
            local += (e4.x + e4.y) + (e4.z + e4.w);
        }
    }
    #pragma unroll
    for (int o = 32; o > 0; o >>= 1) local += __shfl_down(local, o);
    if ((tid & 63) == 0) wred[tid >> 6] = local;
    __syncthreads();
    if (tid == 0)
        ws[OFF_PART + bh*64 + blockIdx.y*8 + blockIdx.x] =
            (wred[0] + wred[1]) + (wred[2] + wred[3]);
}

// ---------------- k_pv: inv-reduce + read e, write attn=e*inv, ctx_partial=(e*inv)@V
// 64 i-rows per block, j-half per blockIdx.x. grid (2,16,32)=1024
__global__ __launch_bounds__(256, 4) void k_pv(
    float* __restrict__ ws, float* __restrict__ attn)
{
    __shared__ float Es[64][68];    // [j][i], ESW-swizzled
    __shared__ float Vs[64][68];    // [j][d]
    __shared__ float s_inv;
    const int jh = blockIdx.x, bh = blockIdx.z, b = bh >> 3, h = bh & 7;
    const int i0 = blockIdx.y * 64;
    const float* vh = ws + OFF_VH + (size_t)bh*NS*DEPTH;
    float* pctx = ws + (jh ? OFF_CTX1 : OFF_CTX0);
    const int tid = threadIdx.x, tx = tid & 15, ty = tid >> 4;
    const int er_ = tid >> 4, ec4 = tid & 15;

    if (tid < 64) {
        float vsum = ws[OFF_PART + bh*64 + tid];
        #pragma unroll
        for (int o = 32; o > 0; o >>= 1) vsum += __shfl_down(vsum, o);
        if (tid == 0) s_inv = 1.0f / vsum;
    }
    __syncthreads();
    const float inv = s_inv;

    float acc[4][4] = {};
    for (int jt = 0; jt < 8; ++jt) {
        const int j0 = jh*512 + jt*64;
        #pragma unroll
        for (int l = 0; l < 4; ++l) {
            const int r = er_ + l*16;          // i row 0..63
            float* ap = attn + ((size_t)bh*NS + i0 + r)*NS + j0 + ec4*4;
            float4 e4 = *(const float4*)ap;
            e4.x *= inv; e4.y *= inv; e4.z *= inv; e4.w *= inv;
            *(float4*)ap = e4;                 // final normalized attn
            Es[ec4*4+0][ESW(ec4*4+0, r)] = e4.x;
            Es[ec4*4+1][ESW(ec4*4+1, r)] = e4.y;
            Es[ec4*4+2][ESW(ec4*4+2, r)] = e4.z;
            Es[ec4*4+3][ESW(ec4*4+3, r)] = e4.w;
            *(float4*)&Vs[r][ec4*4] = *(const float4*)(vh + (size_t)(j0+r)*DEPTH + ec4*4);
        }
        __syncthreads();
        #pragma unroll
        for (int jj = 0; jj < 64; ++jj) {
            const float4 a  = *(const float4*)&Es[jj][ESW(jj, ty*4)];
            const float4 vv = *(const float4*)&Vs[jj][tx*4];
            const float av[4] = {a.x,a.y,a.z,a.w};
            const float vw[4] = {vv.x,vv.y,vv.z,vv.w};
            #pragma unroll
            for (int i = 0; i < 4; ++i)
                #pragma unroll
                for (int d = 0; d < 4; ++d)
                    acc[i][d] = fmaf(av[i], vw[d], acc[i][d]);
        }
        __syncthreads();
    }
    #pragma unroll
    for (int i = 0; i < 4; ++i) {
        const int gi = i0 + ty*4 + i;
        float4 o;
        o.x = acc[i][0]; o.y = acc[i][1]; o.z = acc[i][2]; o.w = acc[i][3];
        *(float4*)(pctx + ((size_t)b*NS + gi)*DM + h*DEPTH + tx*4) = o;
    }
}

// ---------------- out = (ctx0+ctx1)(4096x512) @ wo + b
// 64x64 tile, BK=32, 4x4/thread, double-buffered. grid (8,64)=512
__global__ __launch_bounds__(256, 4) void k_out(
    const float* __restrict__ ws_c, const float* __restrict__ wo,
    const float* __restrict__ bo, float* __restrict__ outp)
{
    __shared__ float As[2][32][68];
    __shared__ float Bs[2][32][68];
    const int tid = threadIdx.x, tx = tid & 15, ty = tid >> 4;
    const int n0 = blockIdx.x * 64, m0 = blockIdx.y * 64;
    const float* c0 = ws_c + OFF_CTX0;
    const float* c1 = ws_c + OFF_CTX1;
    const int am = tid >> 3, ac4 = tid & 7;
    const int br_ = tid >> 4, bc4 = tid & 15;

    float4 ar[2], brg[2];
    #define LOADO(t) { \
        const int kk = (t)*32; \
        _Pragma("unroll") \
        for (int l = 0; l < 2; ++l) { \
            const size_t off = (size_t)(m0 + am + l*32)*DM + kk + ac4*4; \
            const float4 f0 = *(const float4*)(c0 + off); \
            const float4 f1 = *(const float4*)(c1 + off); \
            ar[l].x=f0.x+f1.x; ar[l].y=f0.y+f1.y; ar[l].z=f0.z+f1.z; ar[l].w=f0.w+f1.w; \
        } \
        _Pragma("unroll") \
        for (int l = 0; l < 2; ++l) \
            brg[l] = *(const float4*)(wo + (size_t)(kk + br_ + l*16)*DM + n0 + bc4*4); \
    }
    #define STOREO(bf) { \
        _Pragma("unroll") \
        for (int l = 0; l < 2; ++l) { \
            const int m = am + l*32; \
            As[bf][ac4*4+0][SW3(ac4*4+0, m)] = ar[l].x; \
            As[bf][ac4*4+1][SW3(ac4*4+1, m)] = ar[l].y; \
            As[bf][ac4*4+2][SW3(ac4*4+2, m)] = ar[l].z; \
            As[bf][ac4*4+3][SW3(ac4*4+3, m)] = ar[l].w; \
        } \
        _Pragma("unroll") \
        for (int l = 0; l < 2; ++l) \
            *(float4*)&Bs[bf][br_ + l*16][bc4*4] = brg[l]; \
    }

    float acc[4][4] = {};
    LOADO(0); STOREO(0);
    for (int t = 0; t < 16; ++t) {
        __syncthreads();
        if (t < 15) LOADO(t+1);
        const int bf = t & 1;
        #pragma unroll
        for (int kq = 0; kq < 32; ++kq) {
            const float4 a = *(const float4*)&As[bf][kq][SW3(kq, ty*4)];
            const float4 bb = *(const float4*)&Bs[bf][kq][bc4 == tx ? tx*4 : tx*4];
            const float av[4] = {a.x,a.y,a.z,a.w};
            const float bw[4] = {bb.x,bb.y,bb.z,bb.w};
            #pragma unroll
            for (int i = 0; i < 4; ++i)
                #pragma unroll
                for (int j = 0; j < 4; ++j)
                    acc[i][j] = fmaf(av[i], bw[j], acc[i][j]);
        }
        if (t < 15) STOREO(bf ^ 1);
    }
    const float4 b4 = *(const float4*)(bo + n0 + tx*4);
    #pragma unroll
    for (int i = 0; i < 4; ++i) {
        const int m = m0 + ty*4 + i;
        float4 o;
        o.x = acc[i][0]+b4.x; o.y = acc[i][1]+b4.y;
        o.z = acc[i][2]+b4.z; o.w = acc[i][3]+b4.w;
        *(float4*)(outp + (size_t)m*DM + n0 + tx*4) = o;
    }
    #undef LOADO
    #undef STOREO
}

extern "C" void kernel_launch(void* const* d_in, const int* in_sizes, int n_in,
                              void* d_out, int out_size, void* d_ws, size_t ws_size,
                              hipStream_t stream)
{
    const float* v    = (const float*)d_in[0];
    const float* q    = (const float*)d_in[1];
    const float* k    = (const float*)d_in[2];
    const float* wq_w = (const float*)d_in[3];
    const float* wq_b = (const float*)d_in[4];
    const float* wk_w = (const float*)d_in[5];
    const float* wk_b = (const float*)d_in[6];
    const float* wv_w = (const float*)d_in[7];
    const float* wv_b = (const float*)d_in[8];
    const float* wo_w = (const float*)d_in[9];
    const float* wo_b = (const float*)d_in[10];
    const float* aug_hb = (const float*)d_in[11];
    const float* aug_pi = (const float*)d_in[12];
    const float* aug_at = (const float*)d_in[13];
    const float* t_hb   = (const float*)d_in[14];
    const float* t_pi   = (const float*)d_in[15];
    const float* mask   = (const float*)d_in[16];
    const int*   bnum   = (const int*)d_in[17];

    float* ws   = (float*)d_ws;
    float* outp = (float*)d_out;
    float* attn = (float*)d_out + (size_t)4*NS*DM;

    hipLaunchKernelGGL(k_proj, dim3(8, 32, 3), dim3(256), 0, stream,
                       q, k, v, wq_w, wq_b, wk_w, wk_b, wv_w, wv_b, ws);
    hipLaunchKernelGGL(k_sumexp, dim3(8, 8, 32), dim3(256), 0, stream,
                       ws, t_hb, t_pi, mask, aug_hb, aug_pi, aug_at, bnum, attn);
    hipLaunchKernelGGL(k_pv, dim3(2, 16, 32), dim3(256), 0, stream, ws, attn);
    hipLaunchKernelGGL(k_out, dim3(8, 64), dim3(256), 0, stream,
                       ws, wo_w, wo_b, outp);
}

// Round 5
// 332.386 us; speedup vs baseline: 5.2191x; 5.2191x over previous
//
#include <hip/hip_runtime.h>
#include <math.h>

#define NS 1024
#define DM 512
#define NH 8
#define DEPTH 64

// ws offsets (floats). ctx partials alias qh/kh (dead after k_sumexp).
#define OFF_QH   0
#define OFF_KH   2097152
#define OFF_VH   4194304
#define OFF_CTX0 0
#define OFF_CTX1 2097152
#define OFF_PART 6291456

// swizzles (2-way bank access for the respective lane patterns)
#define SW3(row, col) ((col) ^ ((((row) >> 3) & 3) << 3))   // rows 0..31 scatter
#define ESW(row, col) ((col) ^ ((((row) >> 3) & 7) << 2))   // rows 0..63 scatter

// ---------------- QKV projection: X(4096x512)@W(512x512)+b -> split heads
// 128(M)x64(N) tile, BK=32, 8x4/thread, double-buffered LDS with NAMED-REG
// staging (no arrays -> no scratch). grid (8,32,3)=768 = 3 blocks/CU.
__global__ __launch_bounds__(256, 4) void k_proj(
    const float* __restrict__ q, const float* __restrict__ k, const float* __restrict__ v,
    const float* __restrict__ wq, const float* __restrict__ bq,
    const float* __restrict__ wk, const float* __restrict__ bk,
    const float* __restrict__ wv, const float* __restrict__ bv,
    float* __restrict__ ws)
{
    const float *X, *W, *bias; float* out;
    if (blockIdx.z == 0)      { X=q; W=wq; bias=bq; out=ws+OFF_QH; }
    else if (blockIdx.z == 1) { X=k; W=wk; bias=bk; out=ws+OFF_KH; }
    else                      { X=v; W=wv; bias=bv; out=ws+OFF_VH; }

    __shared__ float As[2][32][132];   // [buf][k][m], SW3-swizzled
    __shared__ float Bs[2][32][68];    // [buf][k][n]
    const int tid = threadIdx.x, tx = tid & 15, ty = tid >> 4;
    const int n0 = blockIdx.x * 64, m0 = blockIdx.y * 128;
    const int am = tid >> 3, ac4 = tid & 7;        // A staging: m base 0..31, k-group 0..7
    const int br_ = tid >> 4, bc4 = tid & 15;      // B staging: k row 0..15, n-group 0..15

    const float* Abase = X + (size_t)(m0 + am)*DM + ac4*4;
    const float* Bbase = W + (size_t)br_*DM + n0 + bc4*4;

    float4 a0, a1, a2, a3, b0, b1;     // named staging registers

    #define LOADP(t) {                                              \
        const int kk = (t)*32;                                      \
        a0 = *(const float4*)(Abase + (size_t)0*32*DM + kk);        \
        a1 = *(const float4*)(Abase + (size_t)1*32*DM + kk);        \
        a2 = *(const float4*)(Abase + (size_t)2*32*DM + kk);        \
        a3 = *(const float4*)(Abase + (size_t)3*32*DM + kk);        \
        b0 = *(const float4*)(Bbase + (size_t)kk*DM);               \
        b1 = *(const float4*)(Bbase + (size_t)(kk+16)*DM);          \
    }
    #define STA(bf, m, f) {                                         \
        As[bf][ac4*4+0][SW3(ac4*4+0, (m))] = f.x;                   \
        As[bf][ac4*4+1][SW3(ac4*4+1, (m))] = f.y;                   \
        As[bf][ac4*4+2][SW3(ac4*4+2, (m))] = f.z;                   \
        As[bf][ac4*4+3][SW3(ac4*4+3, (m))] = f.w;                   \
    }
    #define STOREP(bf) {                                            \
        STA(bf, am +  0, a0); STA(bf, am + 32, a1);                 \
        STA(bf, am + 64, a2); STA(bf, am + 96, a3);                 \
        *(float4*)&Bs[bf][br_     ][bc4*4] = b0;                    \
        *(float4*)&Bs[bf][br_ + 16][bc4*4] = b1;                    \
    }

    float acc[8][4] = {};
    LOADP(0); STOREP(0);
    for (int t = 0; t < 16; ++t) {
        __syncthreads();
        if (t < 15) LOADP(t+1);
        const int bf = t & 1;
        #pragma unroll
        for (int kq = 0; kq < 32; ++kq) {
            const float4 fa0 = *(const float4*)&As[bf][kq][SW3(kq, ty*4)];
            const float4 fa1 = *(const float4*)&As[bf][kq][SW3(kq, 64 + ty*4)];
            const float4 fb0 = *(const float4*)&Bs[bf][kq][tx*4];
            const float av[8] = {fa0.x,fa0.y,fa0.z,fa0.w,fa1.x,fa1.y,fa1.z,fa1.w};
            const float bw[4] = {fb0.x,fb0.y,fb0.z,fb0.w};
            #pragma unroll
            for (int i = 0; i < 8; ++i)
                #pragma unroll
                for (int j = 0; j < 4; ++j)
                    acc[i][j] = fmaf(av[i], bw[j], acc[i][j]);
        }
        if (t < 15) STOREP(bf ^ 1);
    }
    const int h = n0 >> 6;
    const float4 b4 = *(const float4*)(bias + n0 + tx*4);
    #pragma unroll
    for (int i = 0; i < 8; ++i) {
        const int m = m0 + (i>>2)*64 + ty*4 + (i&3);
        const int bb = m >> 10, s = m & 1023;
        float4 o;
        o.x = acc[i][0]+b4.x; o.y = acc[i][1]+b4.y;
        o.z = acc[i][2]+b4.z; o.w = acc[i][3]+b4.w;
        *(float4*)(out + (((size_t)(bb*NH + h))*NS + s)*DEPTH + tx*4) = o;
    }
    #undef LOADP
    #undef STA
    #undef STOREP
}

// ---------------- S = K.Q^T (128x128 tile), e = exp(logits) -> write e + partial sums
__global__ __launch_bounds__(256, 4) void k_sumexp(
    float* __restrict__ ws,
    const float* __restrict__ t_hb, const float* __restrict__ t_pi,
    const float* __restrict__ mask,
    const float* __restrict__ aug_hb, const float* __restrict__ aug_pi,
    const float* __restrict__ aug_at, const int* __restrict__ bnum,
    float* __restrict__ attn)
{
    __shared__ float Ks[32][132];   // [d][i]
    __shared__ float Qs[32][132];   // [d][j]
    __shared__ float wred[4];
    const int bh = blockIdx.z, b = bh >> 3;
    const int i0 = blockIdx.y * 128, j0 = blockIdx.x * 128;
    const float* kh = ws + OFF_KH + (size_t)bh*NS*DEPTH;
    const float* qh = ws + OFF_QH + (size_t)bh*NS*DEPTH;
    const int tid = threadIdx.x, tx = tid & 15, ty = tid >> 4;
    const int ar_ = tid >> 3, ac4 = tid & 7;

    float acc[8][8] = {};
    for (int d0 = 0; d0 < DEPTH; d0 += 32) {
        #pragma unroll
        for (int l = 0; l < 4; ++l) {
            const int r = ar_ + l*32;
            const float4 fk = *(const float4*)(kh + (size_t)(i0+r)*DEPTH + d0 + ac4*4);
            Ks[ac4*4+0][SW3(ac4*4+0, r)]=fk.x; Ks[ac4*4+1][SW3(ac4*4+1, r)]=fk.y;
            Ks[ac4*4+2][SW3(ac4*4+2, r)]=fk.z; Ks[ac4*4+3][SW3(ac4*4+3, r)]=fk.w;
            const float4 fq = *(const float4*)(qh + (size_t)(j0+r)*DEPTH + d0 + ac4*4);
            Qs[ac4*4+0][SW3(ac4*4+0, r)]=fq.x; Qs[ac4*4+1][SW3(ac4*4+1, r)]=fq.y;
            Qs[ac4*4+2][SW3(ac4*4+2, r)]=fq.z; Qs[ac4*4+3][SW3(ac4*4+3, r)]=fq.w;
        }
        __syncthreads();
        #pragma unroll
        for (int d = 0; d < 32; ++d) {
            const float4 fa0 = *(const float4*)&Ks[d][SW3(d, ty*4)];
            const float4 fa1 = *(const float4*)&Ks[d][SW3(d, 64+ty*4)];
            const float4 fb0 = *(const float4*)&Qs[d][SW3(d, tx*4)];
            const float4 fb1 = *(const float4*)&Qs[d][SW3(d, 64+tx*4)];
            const float av[8] = {fa0.x,fa0.y,fa0.z,fa0.w,fa1.x,fa1.y,fa1.z,fa1.w};
            const float bw[8] = {fb0.x,fb0.y,fb0.z,fb0.w,fb1.x,fb1.y,fb1.z,fb1.w};
            #pragma unroll
            for (int i = 0; i < 8; ++i)
                #pragma unroll
                for (int j = 0; j < 8; ++j)
                    acc[i][j] = fmaf(av[i], bw[j], acc[i][j]);
        }
        __syncthreads();
    }

    const int bn = bnum[0];
    const float at = aug_at[bn], hb = aug_hb[bn], pi = aug_pi[bn];
    const float sc_at = 0.125f*at, m_at = -1e9f*at;
    float local = 0.f;
    #pragma unroll
    for (int i = 0; i < 8; ++i) {
        const int gi = i0 + (i>>2)*64 + ty*4 + (i&3);
        const size_t mrow = ((size_t)b*NS + gi)*NS;
        const size_t trow = (size_t)gi*NS;
        const size_t arow = ((size_t)bh*NS + gi)*NS;
        #pragma unroll
        for (int cb = 0; cb < 2; ++cb) {
            const int gj = j0 + cb*64 + tx*4;
            const float4 m4 = *(const float4*)(mask + mrow + gj);
            const float4 h4 = *(const float4*)(t_hb + trow + gj);
            const float4 p4 = *(const float4*)(t_pi + trow + gj);
            float4 e4;
            e4.x = __expf(fmaf(acc[i][cb*4+0], sc_at, fmaf(m4.x, m_at, fmaf(hb, h4.x, pi*p4.x))));
            e4.y = __expf(fmaf(acc[i][cb*4+1], sc_at, fmaf(m4.y, m_at, fmaf(hb, h4.y, pi*p4.y))));
            e4.z = __expf(fmaf(acc[i][cb*4+2], sc_at, fmaf(m4.z, m_at, fmaf(hb, h4.z, pi*p4.z))));
            e4.w = __expf(fmaf(acc[i][cb*4+3], sc_at, fmaf(m4.w, m_at, fmaf(hb, h4.w, pi*p4.w))));
            *(float4*)(attn + arow + gj) = e4;
            local += (e4.x + e4.y) + (e4.z + e4.w);
        }
    }
    #pragma unroll
    for (int o = 32; o > 0; o >>= 1) local += __shfl_down(local, o);
    if ((tid & 63) == 0) wred[tid >> 6] = local;
    __syncthreads();
    if (tid == 0)
        ws[OFF_PART + bh*64 + blockIdx.y*8 + blockIdx.x] =
            (wred[0] + wred[1]) + (wred[2] + wred[3]);
}

// ---------------- k_pv: inv-reduce + read e, write attn=e*inv, ctx_partial=(e*inv)@V
// 64 i-rows per block, j-half per blockIdx.x. grid (2,16,32)=1024
__global__ __launch_bounds__(256, 4) void k_pv(
    float* __restrict__ ws, float* __restrict__ attn)
{
    __shared__ float Es[64][68];    // [j][i], ESW-swizzled
    __shared__ float Vs[64][68];    // [j][d]
    __shared__ float s_inv;
    const int jh = blockIdx.x, bh = blockIdx.z, b = bh >> 3, h = bh & 7;
    const int i0 = blockIdx.y * 64;
    const float* vh = ws + OFF_VH + (size_t)bh*NS*DEPTH;
    float* pctx = ws + (jh ? OFF_CTX1 : OFF_CTX0);
    const int tid = threadIdx.x, tx = tid & 15, ty = tid >> 4;
    const int er_ = tid >> 4, ec4 = tid & 15;

    if (tid < 64) {
        float vsum = ws[OFF_PART + bh*64 + tid];
        #pragma unroll
        for (int o = 32; o > 0; o >>= 1) vsum += __shfl_down(vsum, o);
        if (tid == 0) s_inv = 1.0f / vsum;
    }
    __syncthreads();
    const float inv = s_inv;

    float acc[4][4] = {};
    for (int jt = 0; jt < 8; ++jt) {
        const int j0 = jh*512 + jt*64;
        #pragma unroll
        for (int l = 0; l < 4; ++l) {
            const int r = er_ + l*16;          // i row 0..63
            float* ap = attn + ((size_t)bh*NS + i0 + r)*NS + j0 + ec4*4;
            float4 e4 = *(const float4*)ap;
            e4.x *= inv; e4.y *= inv; e4.z *= inv; e4.w *= inv;
            *(float4*)ap = e4;                 // final normalized attn
            Es[ec4*4+0][ESW(ec4*4+0, r)] = e4.x;
            Es[ec4*4+1][ESW(ec4*4+1, r)] = e4.y;
            Es[ec4*4+2][ESW(ec4*4+2, r)] = e4.z;
            Es[ec4*4+3][ESW(ec4*4+3, r)] = e4.w;
            *(float4*)&Vs[r][ec4*4] = *(const float4*)(vh + (size_t)(j0+r)*DEPTH + ec4*4);
        }
        __syncthreads();
        #pragma unroll
        for (int jj = 0; jj < 64; ++jj) {
            const float4 a  = *(const float4*)&Es[jj][ESW(jj, ty*4)];
            const float4 vv = *(const float4*)&Vs[jj][tx*4];
            const float av[4] = {a.x,a.y,a.z,a.w};
            const float vw[4] = {vv.x,vv.y,vv.z,vv.w};
            #pragma unroll
            for (int i = 0; i < 4; ++i)
                #pragma unroll
                for (int d = 0; d < 4; ++d)
                    acc[i][d] = fmaf(av[i], vw[d], acc[i][d]);
        }
        __syncthreads();
    }
    #pragma unroll
    for (int i = 0; i < 4; ++i) {
        const int gi = i0 + ty*4 + i;
        float4 o;
        o.x = acc[i][0]; o.y = acc[i][1]; o.z = acc[i][2]; o.w = acc[i][3];
        *(float4*)(pctx + ((size_t)b*NS + gi)*DM + h*DEPTH + tx*4) = o;
    }
}

// ---------------- out = (ctx0+ctx1)(4096x512) @ wo + b
// 64x64 tile, BK=32, 4x4/thread, double-buffered, named-reg staging. grid (8,64)=512
__global__ __launch_bounds__(256, 4) void k_out(
    const float* __restrict__ ws_c, const float* __restrict__ wo,
    const float* __restrict__ bo, float* __restrict__ outp)
{
    __shared__ float As[2][32][68];
    __shared__ float Bs[2][32][68];
    const int tid = threadIdx.x, tx = tid & 15, ty = tid >> 4;
    const int n0 = blockIdx.x * 64, m0 = blockIdx.y * 64;
    const float* c0 = ws_c + OFF_CTX0;
    const float* c1 = ws_c + OFF_CTX1;
    const int am = tid >> 3, ac4 = tid & 7;     // m 0..31(+32), k-group 0..7
    const int br_ = tid >> 4, bc4 = tid & 15;   // k 0..15(+16), n-group

    const float* A0 = c0 + (size_t)(m0 + am)*DM + ac4*4;
    const float* A1 = c1 + (size_t)(m0 + am)*DM + ac4*4;
    const float* Bbase = wo + (size_t)br_*DM + n0 + bc4*4;

    float4 a0, a1, b0, b1;
    #define LOADO(t) {                                                \
        const int kk = (t)*32;                                        \
        float4 f0, f1;                                                \
        f0 = *(const float4*)(A0 + kk); f1 = *(const float4*)(A1 + kk); \
        a0.x=f0.x+f1.x; a0.y=f0.y+f1.y; a0.z=f0.z+f1.z; a0.w=f0.w+f1.w; \
        f0 = *(const float4*)(A0 + (size_t)32*DM + kk);               \
        f1 = *(const float4*)(A1 + (size_t)32*DM + kk);               \
        a1.x=f0.x+f1.x; a1.y=f0.y+f1.y; a1.z=f0.z+f1.z; a1.w=f0.w+f1.w; \
        b0 = *(const float4*)(Bbase + (size_t)kk*DM);                 \
        b1 = *(const float4*)(Bbase + (size_t)(kk+16)*DM);            \
    }
    #define STO(bf, m, f) {                                           \
        As[bf][ac4*4+0][SW3(ac4*4+0, (m))] = f.x;                     \
        As[bf][ac4*4+1][SW3(ac4*4+1, (m))] = f.y;                     \
        As[bf][ac4*4+2][SW3(ac4*4+2, (m))] = f.z;                     \
        As[bf][ac4*4+3][SW3(ac4*4+3, (m))] = f.w;                     \
    }
    #define STOREO(bf) {                                              \
        STO(bf, am, a0); STO(bf, am + 32, a1);                        \
        *(float4*)&Bs[bf][br_     ][bc4*4] = b0;                      \
        *(float4*)&Bs[bf][br_ + 16][bc4*4] = b1;                      \
    }

    float acc[4][4] = {};
    LOADO(0); STOREO(0);
    for (int t = 0; t < 16; ++t) {
        __syncthreads();
        if (t < 15) LOADO(t+1);
        const int bf = t & 1;
        #pragma unroll
        for (int kq = 0; kq < 32; ++kq) {
            const float4 fa = *(const float4*)&As[bf][kq][SW3(kq, ty*4)];
            const float4 fb = *(const float4*)&Bs[bf][kq][tx*4];
            const float av[4] = {fa.x,fa.y,fa.z,fa.w};
            const float bw[4] = {fb.x,fb.y,fb.z,fb.w};
            #pragma unroll
            for (int i = 0; i < 4; ++i)
                #pragma unroll
                for (int j = 0; j < 4; ++j)
                    acc[i][j] = fmaf(av[i], bw[j], acc[i][j]);
        }
        if (t < 15) STOREO(bf ^ 1);
    }
    const float4 b4 = *(const float4*)(bo + n0 + tx*4);
    #pragma unroll
    for (int i = 0; i < 4; ++i) {
        const int m = m0 + ty*4 + i;
        float4 o;
        o.x = acc[i][0]+b4.x; o.y = acc[i][1]+b4.y;
        o.z = acc[i][2]+b4.z; o.w = acc[i][3]+b4.w;
        *(float4*)(outp + (size_t)m*DM + n0 + tx*4) = o;
    }
    #undef LOADO
    #undef STO
    #undef STOREO
}

extern "C" void kernel_launch(void* const* d_in, const int* in_sizes, int n_in,
                              void* d_out, int out_size, void* d_ws, size_t ws_size,
                              hipStream_t stream)
{
    const float* v    = (const float*)d_in[0];
    const float* q    = (const float*)d_in[1];
    const float* k    = (const float*)d_in[2];
    const float* wq_w = (const float*)d_in[3];
    const float* wq_b = (const float*)d_in[4];
    const float* wk_w = (const float*)d_in[5];
    const float* wk_b = (const float*)d_in[6];
    const float* wv_w = (const float*)d_in[7];
    const float* wv_b = (const float*)d_in[8];
    const float* wo_w = (const float*)d_in[9];
    const float* wo_b = (const float*)d_in[10];
    const float* aug_hb = (const float*)d_in[11];
    const float* aug_pi = (const float*)d_in[12];
    const float* aug_at = (const float*)d_in[13];
    const float* t_hb   = (const float*)d_in[14];
    const float* t_pi   = (const float*)d_in[15];
    const float* mask   = (const float*)d_in[16];
    const int*   bnum   = (const int*)d_in[17];

    float* ws   = (float*)d_ws;
    float* outp = (float*)d_out;
    float* attn = (float*)d_out + (size_t)4*NS*DM;

    hipLaunchKernelGGL(k_proj, dim3(8, 32, 3), dim3(256), 0, stream,
                       q, k, v, wq_w, wq_b, wk_w, wk_b, wv_w, wv_b, ws);
    hipLaunchKernelGGL(k_sumexp, dim3(8, 8, 32), dim3(256), 0, stream,
                       ws, t_hb, t_pi, mask, aug_hb, aug_pi, aug_at, bnum, attn);
    hipLaunchKernelGGL(k_pv, dim3(2, 16, 32), dim3(256), 0, stream, ws, attn);
    hipLaunchKernelGGL(k_out, dim3(8, 64), dim3(256), 0, stream,
                       ws, wo_w, wo_b, outp);
}

// Round 6
// 303.794 us; speedup vs baseline: 5.7103x; 1.0941x over previous
//
#include <hip/hip_runtime.h>
#include <math.h>

#define NS 1024
#define DM 512
#define NH 8
#define DEPTH 64

// ws offsets (floats). ctx partials alias qh/kh (dead after k_sumexp).
#define OFF_QH   0
#define OFF_KH   2097152
#define OFF_VH   4194304
#define OFF_CTX0 0
#define OFF_CTX1 2097152
#define OFF_PART 6291456

// swizzles (2-way bank access for the respective lane patterns)
#define SW3(row, col) ((col) ^ ((((row) >> 3) & 3) << 3))   // rows 0..31 scatter
#define ESW(row, col) ((col) ^ ((((row) >> 3) & 7) << 2))   // rows 0..63 scatter

// ---------------- QKV projection: X(4096x512)@W(512x512)+b -> split heads
// 128(M)x64(N) tile, BK=32, 8x4/thread, SINGLE-buffered LDS (compiler handles
// scheduling; explicit dbuf blew VGPR to 232 in R5). grid (8,32,3)=768 = 3/CU.
__global__ __launch_bounds__(256) void k_proj(
    const float* __restrict__ q, const float* __restrict__ k, const float* __restrict__ v,
    const float* __restrict__ wq, const float* __restrict__ bq,
    const float* __restrict__ wk, const float* __restrict__ bk,
    const float* __restrict__ wv, const float* __restrict__ bv,
    float* __restrict__ ws)
{
    const float *X, *W, *bias; float* out;
    if (blockIdx.z == 0)      { X=q; W=wq; bias=bq; out=ws+OFF_QH; }
    else if (blockIdx.z == 1) { X=k; W=wk; bias=bk; out=ws+OFF_KH; }
    else                      { X=v; W=wv; bias=bv; out=ws+OFF_VH; }

    __shared__ float As[32][132];   // [k][m], SW3-swizzled
    __shared__ float Bs[32][68];    // [k][n]
    const int tid = threadIdx.x, tx = tid & 15, ty = tid >> 4;
    const int n0 = blockIdx.x * 64, m0 = blockIdx.y * 128;
    const int am = tid >> 3, ac4 = tid & 7;        // A staging: m base 0..31, k-group 0..7
    const int br_ = tid >> 4, bc4 = tid & 15;      // B staging: k row 0..15, n-group 0..15

    float acc[8][4] = {};
    for (int kk = 0; kk < DM; kk += 32) {
        #pragma unroll
        for (int l = 0; l < 4; ++l) {
            const int m = am + l*32;
            const float4 f = *(const float4*)(X + (size_t)(m0+m)*DM + kk + ac4*4);
            As[ac4*4+0][SW3(ac4*4+0, m)] = f.x;
            As[ac4*4+1][SW3(ac4*4+1, m)] = f.y;
            As[ac4*4+2][SW3(ac4*4+2, m)] = f.z;
            As[ac4*4+3][SW3(ac4*4+3, m)] = f.w;
        }
        #pragma unroll
        for (int l = 0; l < 2; ++l)
            *(float4*)&Bs[br_ + l*16][bc4*4] =
                *(const float4*)(W + (size_t)(kk + br_ + l*16)*DM + n0 + bc4*4);
        __syncthreads();
        #pragma unroll
        for (int kq = 0; kq < 32; ++kq) {
            const float4 fa0 = *(const float4*)&As[kq][SW3(kq, ty*4)];
            const float4 fa1 = *(const float4*)&As[kq][SW3(kq, 64 + ty*4)];
            const float4 fb0 = *(const float4*)&Bs[kq][tx*4];
            const float av[8] = {fa0.x,fa0.y,fa0.z,fa0.w,fa1.x,fa1.y,fa1.z,fa1.w};
            const float bw[4] = {fb0.x,fb0.y,fb0.z,fb0.w};
            #pragma unroll
            for (int i = 0; i < 8; ++i)
                #pragma unroll
                for (int j = 0; j < 4; ++j)
                    acc[i][j] = fmaf(av[i], bw[j], acc[i][j]);
        }
        __syncthreads();
    }
    const int h = n0 >> 6;
    const float4 b4 = *(const float4*)(bias + n0 + tx*4);
    #pragma unroll
    for (int i = 0; i < 8; ++i) {
        const int m = m0 + (i>>2)*64 + ty*4 + (i&3);
        const int bb = m >> 10, s = m & 1023;
        float4 o;
        o.x = acc[i][0]+b4.x; o.y = acc[i][1]+b4.y;
        o.z = acc[i][2]+b4.z; o.w = acc[i][3]+b4.w;
        *(float4*)(out + (((size_t)(bb*NH + h))*NS + s)*DEPTH + tx*4) = o;
    }
}

// ---------------- S = K.Q^T (128x128 tile), e = exp(logits) -> write e + partial sums
__global__ __launch_bounds__(256, 4) void k_sumexp(
    float* __restrict__ ws,
    const float* __restrict__ t_hb, const float* __restrict__ t_pi,
    const float* __restrict__ mask,
    const float* __restrict__ aug_hb, const float* __restrict__ aug_pi,
    const float* __restrict__ aug_at, const int* __restrict__ bnum,
    float* __restrict__ attn)
{
    __shared__ float Ks[32][132];   // [d][i]
    __shared__ float Qs[32][132];   // [d][j]
    __shared__ float wred[4];
    const int bh = blockIdx.z, b = bh >> 3;
    const int i0 = blockIdx.y * 128, j0 = blockIdx.x * 128;
    const float* kh = ws + OFF_KH + (size_t)bh*NS*DEPTH;
    const float* qh = ws + OFF_QH + (size_t)bh*NS*DEPTH;
    const int tid = threadIdx.x, tx = tid & 15, ty = tid >> 4;
    const int ar_ = tid >> 3, ac4 = tid & 7;

    float acc[8][8] = {};
    for (int d0 = 0; d0 < DEPTH; d0 += 32) {
        #pragma unroll
        for (int l = 0; l < 4; ++l) {
            const int r = ar_ + l*32;
            const float4 fk = *(const float4*)(kh + (size_t)(i0+r)*DEPTH + d0 + ac4*4);
            Ks[ac4*4+0][SW3(ac4*4+0, r)]=fk.x; Ks[ac4*4+1][SW3(ac4*4+1, r)]=fk.y;
            Ks[ac4*4+2][SW3(ac4*4+2, r)]=fk.z; Ks[ac4*4+3][SW3(ac4*4+3, r)]=fk.w;
            const float4 fq = *(const float4*)(qh + (size_t)(j0+r)*DEPTH + d0 + ac4*4);
            Qs[ac4*4+0][SW3(ac4*4+0, r)]=fq.x; Qs[ac4*4+1][SW3(ac4*4+1, r)]=fq.y;
            Qs[ac4*4+2][SW3(ac4*4+2, r)]=fq.z; Qs[ac4*4+3][SW3(ac4*4+3, r)]=fq.w;
        }
        __syncthreads();
        #pragma unroll
        for (int d = 0; d < 32; ++d) {
            const float4 fa0 = *(const float4*)&Ks[d][SW3(d, ty*4)];
            const float4 fa1 = *(const float4*)&Ks[d][SW3(d, 64+ty*4)];
            const float4 fb0 = *(const float4*)&Qs[d][SW3(d, tx*4)];
            const float4 fb1 = *(const float4*)&Qs[d][SW3(d, 64+tx*4)];
            const float av[8] = {fa0.x,fa0.y,fa0.z,fa0.w,fa1.x,fa1.y,fa1.z,fa1.w};
            const float bw[8] = {fb0.x,fb0.y,fb0.z,fb0.w,fb1.x,fb1.y,fb1.z,fb1.w};
            #pragma unroll
            for (int i = 0; i < 8; ++i)
                #pragma unroll
                for (int j = 0; j < 8; ++j)
                    acc[i][j] = fmaf(av[i], bw[j], acc[i][j]);
        }
        __syncthreads();
    }

    const int bn = bnum[0];
    const float at = aug_at[bn], hb = aug_hb[bn], pi = aug_pi[bn];
    const float sc_at = 0.125f*at, m_at = -1e9f*at;
    float local = 0.f;
    #pragma unroll
    for (int i = 0; i < 8; ++i) {
        const int gi = i0 + (i>>2)*64 + ty*4 + (i&3);
        const size_t mrow = ((size_t)b*NS + gi)*NS;
        const size_t trow = (size_t)gi*NS;
        const size_t arow = ((size_t)bh*NS + gi)*NS;
        #pragma unroll
        for (int cb = 0; cb < 2; ++cb) {
            const int gj = j0 + cb*64 + tx*4;
            const float4 m4 = *(const float4*)(mask + mrow + gj);
            const float4 h4 = *(const float4*)(t_hb + trow + gj);
            const float4 p4 = *(const float4*)(t_pi + trow + gj);
            float4 e4;
            e4.x = __expf(fmaf(acc[i][cb*4+0], sc_at, fmaf(m4.x, m_at, fmaf(hb, h4.x, pi*p4.x))));
            e4.y = __expf(fmaf(acc[i][cb*4+1], sc_at, fmaf(m4.y, m_at, fmaf(hb, h4.y, pi*p4.y))));
            e4.z = __expf(fmaf(acc[i][cb*4+2], sc_at, fmaf(m4.z, m_at, fmaf(hb, h4.z, pi*p4.z))));
            e4.w = __expf(fmaf(acc[i][cb*4+3], sc_at, fmaf(m4.w, m_at, fmaf(hb, h4.w, pi*p4.w))));
            *(float4*)(attn + arow + gj) = e4;
            local += (e4.x + e4.y) + (e4.z + e4.w);
        }
    }
    #pragma unroll
    for (int o = 32; o > 0; o >>= 1) local += __shfl_down(local, o);
    if ((tid & 63) == 0) wred[tid >> 6] = local;
    __syncthreads();
    if (tid == 0)
        ws[OFF_PART + bh*64 + blockIdx.y*8 + blockIdx.x] =
            (wred[0] + wred[1]) + (wred[2] + wred[3]);
}

// ---------------- k_pv: inv-reduce + read e, write attn=e*inv, ctx_partial=(e*inv)@V
// 64 i-rows per block, j-half per blockIdx.x. grid (2,16,32)=1024
__global__ __launch_bounds__(256, 4) void k_pv(
    float* __restrict__ ws, float* __restrict__ attn)
{
    __shared__ float Es[64][68];    // [j][i], ESW-swizzled
    __shared__ float Vs[64][68];    // [j][d]
    __shared__ float s_inv;
    const int jh = blockIdx.x, bh = blockIdx.z, b = bh >> 3, h = bh & 7;
    const int i0 = blockIdx.y * 64;
    const float* vh = ws + OFF_VH + (size_t)bh*NS*DEPTH;
    float* pctx = ws + (jh ? OFF_CTX1 : OFF_CTX0);
    const int tid = threadIdx.x, tx = tid & 15, ty = tid >> 4;
    const int er_ = tid >> 4, ec4 = tid & 15;

    if (tid < 64) {
        float vsum = ws[OFF_PART + bh*64 + tid];
        #pragma unroll
        for (int o = 32; o > 0; o >>= 1) vsum += __shfl_down(vsum, o);
        if (tid == 0) s_inv = 1.0f / vsum;
    }
    __syncthreads();
    const float inv = s_inv;

    float acc[4][4] = {};
    for (int jt = 0; jt < 8; ++jt) {
        const int j0 = jh*512 + jt*64;
        #pragma unroll
        for (int l = 0; l < 4; ++l) {
            const int r = er_ + l*16;          // i row 0..63
            float* ap = attn + ((size_t)bh*NS + i0 + r)*NS + j0 + ec4*4;
            float4 e4 = *(const float4*)ap;
            e4.x *= inv; e4.y *= inv; e4.z *= inv; e4.w *= inv;
            *(float4*)ap = e4;                 // final normalized attn
            Es[ec4*4+0][ESW(ec4*4+0, r)] = e4.x;
            Es[ec4*4+1][ESW(ec4*4+1, r)] = e4.y;
            Es[ec4*4+2][ESW(ec4*4+2, r)] = e4.z;
            Es[ec4*4+3][ESW(ec4*4+3, r)] = e4.w;
            *(float4*)&Vs[r][ec4*4] = *(const float4*)(vh + (size_t)(j0+r)*DEPTH + ec4*4);
        }
        __syncthreads();
        #pragma unroll
        for (int jj = 0; jj < 64; ++jj) {
            const float4 a  = *(const float4*)&Es[jj][ESW(jj, ty*4)];
            const float4 vv = *(const float4*)&Vs[jj][tx*4];
            const float av[4] = {a.x,a.y,a.z,a.w};
            const float vw[4] = {vv.x,vv.y,vv.z,vv.w};
            #pragma unroll
            for (int i = 0; i < 4; ++i)
                #pragma unroll
                for (int d = 0; d < 4; ++d)
                    acc[i][d] = fmaf(av[i], vw[d], acc[i][d]);
        }
        __syncthreads();
    }
    #pragma unroll
    for (int i = 0; i < 4; ++i) {
        const int gi = i0 + ty*4 + i;
        float4 o;
        o.x = acc[i][0]; o.y = acc[i][1]; o.z = acc[i][2]; o.w = acc[i][3];
        *(float4*)(pctx + ((size_t)b*NS + gi)*DM + h*DEPTH + tx*4) = o;
    }
}

// ---------------- out = (ctx0+ctx1)(4096x512) @ wo + b
// 64x64 tile, BK=32, 4x4/thread, double-buffered, named-reg staging. grid (8,64)=512
__global__ __launch_bounds__(256, 4) void k_out(
    const float* __restrict__ ws_c, const float* __restrict__ wo,
    const float* __restrict__ bo, float* __restrict__ outp)
{
    __shared__ float As[2][32][68];
    __shared__ float Bs[2][32][68];
    const int tid = threadIdx.x, tx = tid & 15, ty = tid >> 4;
    const int n0 = blockIdx.x * 64, m0 = blockIdx.y * 64;
    const float* c0 = ws_c + OFF_CTX0;
    const float* c1 = ws_c + OFF_CTX1;
    const int am = tid >> 3, ac4 = tid & 7;     // m 0..31(+32), k-group 0..7
    const int br_ = tid >> 4, bc4 = tid & 15;   // k 0..15(+16), n-group

    const float* A0 = c0 + (size_t)(m0 + am)*DM + ac4*4;
    const float* A1 = c1 + (size_t)(m0 + am)*DM + ac4*4;
    const float* Bbase = wo + (size_t)br_*DM + n0 + bc4*4;

    float4 a0, a1, b0, b1;
    #define LOADO(t) {                                                \
        const int kk = (t)*32;                                        \
        float4 f0, f1;                                                \
        f0 = *(const float4*)(A0 + kk); f1 = *(const float4*)(A1 + kk); \
        a0.x=f0.x+f1.x; a0.y=f0.y+f1.y; a0.z=f0.z+f1.z; a0.w=f0.w+f1.w; \
        f0 = *(const float4*)(A0 + (size_t)32*DM + kk);               \
        f1 = *(const float4*)(A1 + (size_t)32*DM + kk);               \
        a1.x=f0.x+f1.x; a1.y=f0.y+f1.y; a1.z=f0.z+f1.z; a1.w=f0.w+f1.w; \
        b0 = *(const float4*)(Bbase + (size_t)kk*DM);                 \
        b1 = *(const float4*)(Bbase + (size_t)(kk+16)*DM);            \
    }
    #define STO(bf, m, f) {                                           \
        As[bf][ac4*4+0][SW3(ac4*4+0, (m))] = f.x;                     \
        As[bf][ac4*4+1][SW3(ac4*4+1, (m))] = f.y;                     \
        As[bf][ac4*4+2][SW3(ac4*4+2, (m))] = f.z;                     \
        As[bf][ac4*4+3][SW3(ac4*4+3, (m))] = f.w;                     \
    }
    #define STOREO(bf) {                                              \
        STO(bf, am, a0); STO(bf, am + 32, a1);                        \
        *(float4*)&Bs[bf][br_     ][bc4*4] = b0;                      \
        *(float4*)&Bs[bf][br_ + 16][bc4*4] = b1;                      \
    }

    float acc[4][4] = {};
    LOADO(0); STOREO(0);
    for (int t = 0; t < 16; ++t) {
        __syncthreads();
        if (t < 15) LOADO(t+1);
        const int bf = t & 1;
        #pragma unroll
        for (int kq = 0; kq < 32; ++kq) {
            const float4 fa = *(const float4*)&As[bf][kq][SW3(kq, ty*4)];
            const float4 fb = *(const float4*)&Bs[bf][kq][tx*4];
            const float av[4] = {fa.x,fa.y,fa.z,fa.w};
            const float bw[4] = {fb.x,fb.y,fb.z,fb.w};
            #pragma unroll
            for (int i = 0; i < 4; ++i)
                #pragma unroll
                for (int j = 0; j < 4; ++j)
                    acc[i][j] = fmaf(av[i], bw[j], acc[i][j]);
        }
        if (t < 15) STOREO(bf ^ 1);
    }
    const float4 b4 = *(const float4*)(bo + n0 + tx*4);
    #pragma unroll
    for (int i = 0; i < 4; ++i) {
        const int m = m0 + ty*4 + i;
        float4 o;
        o.x = acc[i][0]+b4.x; o.y = acc[i][1]+b4.y;
        o.z = acc[i][2]+b4.z; o.w = acc[i][3]+b4.w;
        *(float4*)(outp + (size_t)m*DM + n0 + tx*4) = o;
    }
    #undef LOADO
    #undef STO
    #undef STOREO
}

extern "C" void kernel_launch(void* const* d_in, const int* in_sizes, int n_in,
                              void* d_out, int out_size, void* d_ws, size_t ws_size,
                              hipStream_t stream)
{
    const float* v    = (const float*)d_in[0];
    const float* q    = (const float*)d_in[1];
    const float* k    = (const float*)d_in[2];
    const float* wq_w = (const float*)d_in[3];
    const float* wq_b = (const float*)d_in[4];
    const float* wk_w = (const float*)d_in[5];
    const float* wk_b = (const float*)d_in[6];
    const float* wv_w = (const float*)d_in[7];
    const float* wv_b = (const float*)d_in[8];
    const float* wo_w = (const float*)d_in[9];
    const float* wo_b = (const float*)d_in[10];
    const float* aug_hb = (const float*)d_in[11];
    const float* aug_pi = (const float*)d_in[12];
    const float* aug_at = (const float*)d_in[13];
    const float* t_hb   = (const float*)d_in[14];
    const float* t_pi   = (const float*)d_in[15];
    const float* mask   = (const float*)d_in[16];
    const int*   bnum   = (const int*)d_in[17];

    float* ws   = (float*)d_ws;
    float* outp = (float*)d_out;
    float* attn = (float*)d_out + (size_t)4*NS*DM;

    hipLaunchKernelGGL(k_proj, dim3(8, 32, 3), dim3(256), 0, stream,
                       q, k, v, wq_w, wq_b, wk_w, wk_b, wv_w, wv_b, ws);
    hipLaunchKernelGGL(k_sumexp, dim3(8, 8, 32), dim3(256), 0, stream,
                       ws, t_hb, t_pi, mask, aug_hb, aug_pi, aug_at, bnum, attn);
    hipLaunchKernelGGL(k_pv, dim3(2, 16, 32), dim3(256), 0, stream, ws, attn);
    hipLaunchKernelGGL(k_out, dim3(8, 64), dim3(256), 0, stream,
                       ws, wo_w, wo_b, outp);
}

// Round 7
// 295.317 us; speedup vs baseline: 5.8742x; 1.0287x over previous
//
#include <hip/hip_runtime.h>
#include <math.h>

#define NS 1024
#define DM 512
#define NH 8
#define DEPTH 64

// ws offsets (floats). ctx partials alias qh/kh (dead after k_sumexp).
#define OFF_QH   0
#define OFF_KH   2097152
#define OFF_VH   4194304
#define OFF_CTX0 0
#define OFF_CTX1 2097152
#define OFF_PART 6291456

// swizzles (2-way bank access for the respective lane patterns)
#define SW3(row, col) ((col) ^ ((((row) >> 3) & 3) << 3))   // rows 0..31 scatter
#define ESW(row, col) ((col) ^ ((((row) >> 3) & 7) << 2))   // rows 0..63 scatter

typedef float f4 __attribute__((ext_vector_type(4)));

// ---------------- QKV projection: X(4096x512)@W(512x512)+b -> split heads
// 128(M)x64(N) tile, BK=32, 8x4/thread, single-buffered.
// XCD swizzle: all 8 n-tiles of one X-panel share f%8 -> same XCD L2.
__global__ __launch_bounds__(256, 3) void k_proj(
    const float* __restrict__ q, const float* __restrict__ k, const float* __restrict__ v,
    const float* __restrict__ wq, const float* __restrict__ bq,
    const float* __restrict__ wk, const float* __restrict__ bk,
    const float* __restrict__ wv, const float* __restrict__ bv,
    float* __restrict__ ws)
{
    const float *X, *W, *bias; float* out;
    if (blockIdx.z == 0)      { X=q; W=wq; bias=bq; out=ws+OFF_QH; }
    else if (blockIdx.z == 1) { X=k; W=wk; bias=bk; out=ws+OFF_KH; }
    else                      { X=v; W=wv; bias=bv; out=ws+OFF_VH; }

    // XCD-aware remap: hardware XCD = (x + 8y)%8; make same-m-panel blocks share it.
    const int f = blockIdx.x + (blockIdx.y << 3);       // 0..255
    const int n0 = (f >> 5) * 64;
    const int m0 = (f & 31) * 128;

    __shared__ float As[32][132];   // [k][m], SW3-swizzled
    __shared__ float Bs[32][68];    // [k][n]
    const int tid = threadIdx.x, tx = tid & 15, ty = tid >> 4;
    const int am = tid >> 3, ac4 = tid & 7;        // A staging: m base 0..31, k-group 0..7
    const int br_ = tid >> 4, bc4 = tid & 15;      // B staging: k row 0..15, n-group 0..15

    float acc[8][4] = {};
    for (int kk = 0; kk < DM; kk += 32) {
        #pragma unroll
        for (int l = 0; l < 4; ++l) {
            const int m = am + l*32;
            const float4 fx = *(const float4*)(X + (size_t)(m0+m)*DM + kk + ac4*4);
            As[ac4*4+0][SW3(ac4*4+0, m)] = fx.x;
            As[ac4*4+1][SW3(ac4*4+1, m)] = fx.y;
            As[ac4*4+2][SW3(ac4*4+2, m)] = fx.z;
            As[ac4*4+3][SW3(ac4*4+3, m)] = fx.w;
        }
        #pragma unroll
        for (int l = 0; l < 2; ++l)
            *(float4*)&Bs[br_ + l*16][bc4*4] =
                *(const float4*)(W + (size_t)(kk + br_ + l*16)*DM + n0 + bc4*4);
        __syncthreads();
        #pragma unroll
        for (int kq = 0; kq < 32; ++kq) {
            const float4 fa0 = *(const float4*)&As[kq][SW3(kq, ty*4)];
            const float4 fa1 = *(const float4*)&As[kq][SW3(kq, 64 + ty*4)];
            const float4 fb0 = *(const float4*)&Bs[kq][tx*4];
            const float av[8] = {fa0.x,fa0.y,fa0.z,fa0.w,fa1.x,fa1.y,fa1.z,fa1.w};
            const float bw[4] = {fb0.x,fb0.y,fb0.z,fb0.w};
            #pragma unroll
            for (int i = 0; i < 8; ++i)
                #pragma unroll
                for (int j = 0; j < 4; ++j)
                    acc[i][j] = fmaf(av[i], bw[j], acc[i][j]);
        }
        __syncthreads();
    }
    const int h = n0 >> 6;
    const float4 b4 = *(const float4*)(bias + n0 + tx*4);
    #pragma unroll
    for (int i = 0; i < 8; ++i) {
        const int m = m0 + (i>>2)*64 + ty*4 + (i&3);
        const int bb = m >> 10, s = m & 1023;
        float4 o;
        o.x = acc[i][0]+b4.x; o.y = acc[i][1]+b4.y;
        o.z = acc[i][2]+b4.z; o.w = acc[i][3]+b4.w;
        *(float4*)(out + (((size_t)(bb*NH + h))*NS + s)*DEPTH + tx*4) = o;
    }
}

// ---------------- S = K.Q^T (128x128 tile), e = exp(logits) -> nt-write e + partial sums
// Rect XCD grouping: each XCD gets a 4(i)x2(j) rectangle -> kh x4, qh x2 fetch.
__global__ __launch_bounds__(256, 4) void k_sumexp(
    float* __restrict__ ws,
    const float* __restrict__ t_hb, const float* __restrict__ t_pi,
    const float* __restrict__ mask,
    const float* __restrict__ aug_hb, const float* __restrict__ aug_pi,
    const float* __restrict__ aug_at, const int* __restrict__ bnum,
    float* __restrict__ attn)
{
    __shared__ float Ks[32][132];   // [d][i]
    __shared__ float Qs[32][132];   // [d][j]
    __shared__ float wred[4];
    const int bh = blockIdx.z, b = bh >> 3;
    // hw XCD = (x + 8y)%8 (z adds multiples of 64 -> residue preserved)
    const int f = blockIdx.x + (blockIdx.y << 3);  // 0..63
    const int r = f & 7, qq = f >> 3;
    const int it = ((r & 1) << 2) | (qq & 3);      // 0..7
    const int jt = ((r >> 1) << 1) | (qq >> 2);    // 0..7
    const int i0 = it * 128, j0 = jt * 128;
    const float* kh = ws + OFF_KH + (size_t)bh*NS*DEPTH;
    const float* qh = ws + OFF_QH + (size_t)bh*NS*DEPTH;
    const int tid = threadIdx.x, tx = tid & 15, ty = tid >> 4;
    const int ar_ = tid >> 3, ac4 = tid & 7;

    float acc[8][8] = {};
    for (int d0 = 0; d0 < DEPTH; d0 += 32) {
        #pragma unroll
        for (int l = 0; l < 4; ++l) {
            const int rr = ar_ + l*32;
            const float4 fk = *(const float4*)(kh + (size_t)(i0+rr)*DEPTH + d0 + ac4*4);
            Ks[ac4*4+0][SW3(ac4*4+0, rr)]=fk.x; Ks[ac4*4+1][SW3(ac4*4+1, rr)]=fk.y;
            Ks[ac4*4+2][SW3(ac4*4+2, rr)]=fk.z; Ks[ac4*4+3][SW3(ac4*4+3, rr)]=fk.w;
            const float4 fq = *(const float4*)(qh + (size_t)(j0+rr)*DEPTH + d0 + ac4*4);
            Qs[ac4*4+0][SW3(ac4*4+0, rr)]=fq.x; Qs[ac4*4+1][SW3(ac4*4+1, rr)]=fq.y;
            Qs[ac4*4+2][SW3(ac4*4+2, rr)]=fq.z; Qs[ac4*4+3][SW3(ac4*4+3, rr)]=fq.w;
        }
        __syncthreads();
        #pragma unroll
        for (int d = 0; d < 32; ++d) {
            const float4 fa0 = *(const float4*)&Ks[d][SW3(d, ty*4)];
            const float4 fa1 = *(const float4*)&Ks[d][SW3(d, 64+ty*4)];
            const float4 fb0 = *(const float4*)&Qs[d][SW3(d, tx*4)];
            const float4 fb1 = *(const float4*)&Qs[d][SW3(d, 64+tx*4)];
            const float av[8] = {fa0.x,fa0.y,fa0.z,fa0.w,fa1.x,fa1.y,fa1.z,fa1.w};
            const float bw[8] = {fb0.x,fb0.y,fb0.z,fb0.w,fb1.x,fb1.y,fb1.z,fb1.w};
            #pragma unroll
            for (int i = 0; i < 8; ++i)
                #pragma unroll
                for (int j = 0; j < 8; ++j)
                    acc[i][j] = fmaf(av[i], bw[j], acc[i][j]);
        }
        __syncthreads();
    }

    const int bn = bnum[0];
    const float at = aug_at[bn], hb = aug_hb[bn], pi = aug_pi[bn];
    const float sc_at = 0.125f*at, m_at = -1e9f*at;
    float local = 0.f;
    #pragma unroll
    for (int i = 0; i < 8; ++i) {
        const int gi = i0 + (i>>2)*64 + ty*4 + (i&3);
        const size_t mrow = ((size_t)b*NS + gi)*NS;
        const size_t trow = (size_t)gi*NS;
        const size_t arow = ((size_t)bh*NS + gi)*NS;
        #pragma unroll
        for (int cb = 0; cb < 2; ++cb) {
            const int gj = j0 + cb*64 + tx*4;
            const float4 m4 = *(const float4*)(mask + mrow + gj);
            const float4 h4 = *(const float4*)(t_hb + trow + gj);
            const float4 p4 = *(const float4*)(t_pi + trow + gj);
            f4 e4;
            e4.x = __expf(fmaf(acc[i][cb*4+0], sc_at, fmaf(m4.x, m_at, fmaf(hb, h4.x, pi*p4.x))));
            e4.y = __expf(fmaf(acc[i][cb*4+1], sc_at, fmaf(m4.y, m_at, fmaf(hb, h4.y, pi*p4.y))));
            e4.z = __expf(fmaf(acc[i][cb*4+2], sc_at, fmaf(m4.z, m_at, fmaf(hb, h4.z, pi*p4.z))));
            e4.w = __expf(fmaf(acc[i][cb*4+3], sc_at, fmaf(m4.w, m_at, fmaf(hb, h4.w, pi*p4.w))));
            __builtin_nontemporal_store(e4, (f4*)(attn + arow + gj));
            local += (e4.x + e4.y) + (e4.z + e4.w);
        }
    }
    #pragma unroll
    for (int o = 32; o > 0; o >>= 1) local += __shfl_down(local, o);
    if ((tid & 63) == 0) wred[tid >> 6] = local;
    __syncthreads();
    if (tid == 0)
        ws[OFF_PART + bh*64 + it*8 + jt] =
            (wred[0] + wred[1]) + (wred[2] + wred[3]);
}

// ---------------- k_pv: inv-reduce + nt-read e, nt-write attn=e*inv, ctx_partial=(e*inv)@V
// XCD swizzle: all 32 blocks of one bh share F%8 -> vh stays in one XCD's L2.
__global__ __launch_bounds__(256, 4) void k_pv(
    float* __restrict__ ws, float* __restrict__ attn)
{
    __shared__ float Es[64][68];    // [j][i], ESW-swizzled
    __shared__ float Vs[64][68];    // [j][d]
    __shared__ float s_inv;
    const int F = blockIdx.x + (blockIdx.y << 1) + (blockIdx.z << 5);  // 0..1023
    const int r = F & 7, s = F >> 3;       // hw XCD = r
    const int bh = (r << 2) | (s & 3);     // 0..31 — co-located per XCD
    const int w = s >> 2;                  // 0..31
    const int i0 = (w >> 1) * 64;
    const int jh = w & 1;
    const int b = bh >> 3, h = bh & 7;
    const float* vh = ws + OFF_VH + (size_t)bh*NS*DEPTH;
    float* pctx = ws + (jh ? OFF_CTX1 : OFF_CTX0);
    const int tid = threadIdx.x, tx = tid & 15, ty = tid >> 4;
    const int er_ = tid >> 4, ec4 = tid & 15;

    if (tid < 64) {
        float vsum = ws[OFF_PART + bh*64 + tid];
        #pragma unroll
        for (int o = 32; o > 0; o >>= 1) vsum += __shfl_down(vsum, o);
        if (tid == 0) s_inv = 1.0f / vsum;
    }
    __syncthreads();
    const float inv = s_inv;

    float acc[4][4] = {};
    for (int jt = 0; jt < 8; ++jt) {
        const int j0 = jh*512 + jt*64;
        #pragma unroll
        for (int l = 0; l < 4; ++l) {
            const int rr = er_ + l*16;         // i row 0..63
            float* ap = attn + ((size_t)bh*NS + i0 + rr)*NS + j0 + ec4*4;
            f4 e4 = __builtin_nontemporal_load((const f4*)ap);
            e4 *= inv;
            __builtin_nontemporal_store(e4, (f4*)ap);   // final normalized attn
            Es[ec4*4+0][ESW(ec4*4+0, rr)] = e4.x;
            Es[ec4*4+1][ESW(ec4*4+1, rr)] = e4.y;
            Es[ec4*4+2][ESW(ec4*4+2, rr)] = e4.z;
            Es[ec4*4+3][ESW(ec4*4+3, rr)] = e4.w;
            *(float4*)&Vs[rr][ec4*4] = *(const float4*)(vh + (size_t)(j0+rr)*DEPTH + ec4*4);
        }
        __syncthreads();
        #pragma unroll
        for (int jj = 0; jj < 64; ++jj) {
            const float4 a  = *(const float4*)&Es[jj][ESW(jj, ty*4)];
            const float4 vv = *(const float4*)&Vs[jj][tx*4];
            const float av[4] = {a.x,a.y,a.z,a.w};
            const float vw[4] = {vv.x,vv.y,vv.z,vv.w};
            #pragma unroll
            for (int i = 0; i < 4; ++i)
                #pragma unroll
                for (int d = 0; d < 4; ++d)
                    acc[i][d] = fmaf(av[i], vw[d], acc[i][d]);
        }
        __syncthreads();
    }
    #pragma unroll
    for (int i = 0; i < 4; ++i) {
        const int gi = i0 + ty*4 + i;
        float4 o;
        o.x = acc[i][0]; o.y = acc[i][1]; o.z = acc[i][2]; o.w = acc[i][3];
        *(float4*)(pctx + ((size_t)b*NS + gi)*DM + h*DEPTH + tx*4) = o;
    }
}

// ---------------- out = (ctx0+ctx1)(4096x512) @ wo + b
// 64x64 tile, BK=32, 4x4/thread, double-buffered, named-reg staging. grid (8,64)=512
__global__ __launch_bounds__(256, 4) void k_out(
    const float* __restrict__ ws_c, const float* __restrict__ wo,
    const float* __restrict__ bo, float* __restrict__ outp)
{
    __shared__ float As[2][32][68];
    __shared__ float Bs[2][32][68];
    const int tid = threadIdx.x, tx = tid & 15, ty = tid >> 4;
    const int n0 = blockIdx.x * 64, m0 = blockIdx.y * 64;
    const float* c0 = ws_c + OFF_CTX0;
    const float* c1 = ws_c + OFF_CTX1;
    const int am = tid >> 3, ac4 = tid & 7;     // m 0..31(+32), k-group 0..7
    const int br_ = tid >> 4, bc4 = tid & 15;   // k 0..15(+16), n-group

    const float* A0 = c0 + (size_t)(m0 + am)*DM + ac4*4;
    const float* A1 = c1 + (size_t)(m0 + am)*DM + ac4*4;
    const float* Bbase = wo + (size_t)br_*DM + n0 + bc4*4;

    float4 a0, a1, b0, b1;
    #define LOADO(t) {                                                \
        const int kk = (t)*32;                                        \
        float4 f0, f1;                                                \
        f0 = *(const float4*)(A0 + kk); f1 = *(const float4*)(A1 + kk); \
        a0.x=f0.x+f1.x; a0.y=f0.y+f1.y; a0.z=f0.z+f1.z; a0.w=f0.w+f1.w; \
        f0 = *(const float4*)(A0 + (size_t)32*DM + kk);               \
        f1 = *(const float4*)(A1 + (size_t)32*DM + kk);               \
        a1.x=f0.x+f1.x; a1.y=f0.y+f1.y; a1.z=f0.z+f1.z; a1.w=f0.w+f1.w; \
        b0 = *(const float4*)(Bbase + (size_t)kk*DM);                 \
        b1 = *(const float4*)(Bbase + (size_t)(kk+16)*DM);            \
    }
    #define STO(bf, m, f) {                                           \
        As[bf][ac4*4+0][SW3(ac4*4+0, (m))] = f.x;                     \
        As[bf][ac4*4+1][SW3(ac4*4+1, (m))] = f.y;                     \
        As[bf][ac4*4+2][SW3(ac4*4+2, (m))] = f.z;                     \
        As[bf][ac4*4+3][SW3(ac4*4+3, (m))] = f.w;                     \
    }
    #define STOREO(bf) {                                              \
        STO(bf, am, a0); STO(bf, am + 32, a1);                        \
        *(float4*)&Bs[bf][br_     ][bc4*4] = b0;                      \
        *(float4*)&Bs[bf][br_ + 16][bc4*4] = b1;                      \
    }

    float acc[4][4] = {};
    LOADO(0); STOREO(0);
    for (int t = 0; t < 16; ++t) {
        __syncthreads();
        if (t < 15) LOADO(t+1);
        const int bf = t & 1;
        #pragma unroll
        for (int kq = 0; kq < 32; ++kq) {
            const float4 fa = *(const float4*)&As[bf][kq][SW3(kq, ty*4)];
            const float4 fb = *(const float4*)&Bs[bf][kq][tx*4];
            const float av[4] = {fa.x,fa.y,fa.z,fa.w};
            const float bw[4] = {fb.x,fb.y,fb.z,fb.w};
            #pragma unroll
            for (int i = 0; i < 4; ++i)
                #pragma unroll
                for (int j = 0; j < 4; ++j)
                    acc[i][j] = fmaf(av[i], bw[j], acc[i][j]);
        }
        if (t < 15) STOREO(bf ^ 1);
    }
    const float4 b4 = *(const float4*)(bo + n0 + tx*4);
    #pragma unroll
    for (int i = 0; i < 4; ++i) {
        const int m = m0 + ty*4 + i;
        float4 o;
        o.x = acc[i][0]+b4.x; o.y = acc[i][1]+b4.y;
        o.z = acc[i][2]+b4.z; o.w = acc[i][3]+b4.w;
        *(float4*)(outp + (size_t)m*DM + n0 + tx*4) = o;
    }
    #undef LOADO
    #undef STO
    #undef STOREO
}

extern "C" void kernel_launch(void* const* d_in, const int* in_sizes, int n_in,
                              void* d_out, int out_size, void* d_ws, size_t ws_size,
                              hipStream_t stream)
{
    const float* v    = (const float*)d_in[0];
    const float* q    = (const float*)d_in[1];
    const float* k    = (const float*)d_in[2];
    const float* wq_w = (const float*)d_in[3];
    const float* wq_b = (const float*)d_in[4];
    const float* wk_w = (const float*)d_in[5];
    const float* wk_b = (const float*)d_in[6];
    const float* wv_w = (const float*)d_in[7];
    const float* wv_b = (const float*)d_in[8];
    const float* wo_w = (const float*)d_in[9];
    const float* wo_b = (const float*)d_in[10];
    const float* aug_hb = (const float*)d_in[11];
    const float* aug_pi = (const float*)d_in[12];
    const float* aug_at = (const float*)d_in[13];
    const float* t_hb   = (const float*)d_in[14];
    const float* t_pi   = (const float*)d_in[15];
    const float* mask   = (const float*)d_in[16];
    const int*   bnum   = (const int*)d_in[17];

    float* ws   = (float*)d_ws;
    float* outp = (float*)d_out;
    float* attn = (float*)d_out + (size_t)4*NS*DM;

    hipLaunchKernelGGL(k_proj, dim3(8, 32, 3), dim3(256), 0, stream,
                       q, k, v, wq_w, wq_b, wk_w, wk_b, wv_w, wv_b, ws);
    hipLaunchKernelGGL(k_sumexp, dim3(8, 8, 32), dim3(256), 0, stream,
                       ws, t_hb, t_pi, mask, aug_hb, aug_pi, aug_at, bnum, attn);
    hipLaunchKernelGGL(k_pv, dim3(2, 16, 32), dim3(256), 0, stream, ws, attn);
    hipLaunchKernelGGL(k_out, dim3(8, 64), dim3(256), 0, stream,
                       ws, wo_w, wo_b, outp);
}

// Round 11
// 259.824 us; speedup vs baseline: 6.6767x; 1.1366x over previous
//
#include <hip/hip_runtime.h>
#include <math.h>

#define NS 1024
#define DM 512
#define NH 8
#define DEPTH 64

// ws offsets (floats). ctx partials alias qh/kh (dead after k_sumexp).
// TOTAL ws usage: 6293504 floats = 25.17 MB (same as proven R3-R7 rounds).
#define OFF_QH   0
#define OFF_KH   2097152
#define OFF_VH   4194304
#define OFF_CTX0 0
#define OFF_CTX1 2097152
#define OFF_PART 6291456
// wo bricks alias the VH region (dead after k_pv): 262144 floats at OFF_VH.

#define SW3(row, col) ((col) ^ ((((row) >> 3) & 3) << 3))   // rows 0..31 scatter
#define ESW(row, col) ((col) ^ ((((row) >> 3) & 7) << 2))   // rows 0..63 scatter

#define LO_SCALE 2048.0f
#define LO_INV   (1.0f/2048.0f)
#define F16_MIN_NORM 6.1035156e-5f
#define ASCALE   4096.0f            // k_out input pre-scale (ctx ~ 3e-5)
#define AUNSCALE (1.0f/4096.0f)

typedef float f4 __attribute__((ext_vector_type(4)));
typedef _Float16 h8 __attribute__((ext_vector_type(8)));
typedef float f32x4v __attribute__((ext_vector_type(4)));

// guarded hi: never produce a denormal hi; residual (scaled) goes to lo.
#define SPLIT1(x, hi_e, lo_e) {                                          \
    const float x_ = (x);                                                \
    _Float16 t = (fabsf(x_) >= F16_MIN_NORM) ? (_Float16)x_ : (_Float16)0.f; \
    hi_e = t;                                                            \
    lo_e = (_Float16)((x_ - (float)t) * LO_SCALE);                       \
}

#define SPLIT8(u0, u1, hi, lo) {                                         \
    SPLIT1(u0.x, hi[0], lo[0]) SPLIT1(u0.y, hi[1], lo[1])                \
    SPLIT1(u0.z, hi[2], lo[2]) SPLIT1(u0.w, hi[3], lo[3])                \
    SPLIT1(u1.x, hi[4], lo[4]) SPLIT1(u1.y, hi[5], lo[5])                \
    SPLIT1(u1.z, hi[6], lo[6]) SPLIT1(u1.w, hi[7], lo[7])                \
}

// 3-MFMA scaled split product: accH += ah*bh ; accM += al*bh + ah*bl
#define MM(accH, accM, a_h, a_l, b_h, b_l) {                                   \
    accH = __builtin_amdgcn_mfma_f32_16x16x32_f16(a_h, b_h, accH, 0, 0, 0);    \
    accM = __builtin_amdgcn_mfma_f32_16x16x32_f16(a_l, b_h, accM, 0, 0, 0);    \
    accM = __builtin_amdgcn_mfma_f32_16x16x32_f16(a_h, b_l, accM, 0, 0, 0);    \
}

// ---- prep body: W[512][512] fp32 -> fp16 hi + scaled-lo bricks (262144 halves each)
// brick addr (halves) = (n>>4)*8192 + (k>>3)*128 + (n&15)*8 + (k&7)
__device__ __forceinline__ void prep_one(
    const float* __restrict__ W, _Float16* __restrict__ whi,
    _Float16* __restrict__ wlo, int g)
{
    const int kk = g >> 7;
    const int n  = (g & 127) * 4;
    const float4 f = *(const float4*)(W + (size_t)kk * DM + n);
    const int gbase = (kk >> 3) * 128 + (kk & 7);
    #define PREP1(val, nn) {                                             \
        const int a_ = ((nn) >> 4) * 8192 + gbase + ((nn) & 15) * 8;     \
        _Float16 h_; _Float16 l_;                                        \
        SPLIT1(val, h_, l_)                                              \
        whi[a_] = h_; wlo[a_] = l_;                                      \
    }
    PREP1(f.x, n + 0) PREP1(f.y, n + 1) PREP1(f.z, n + 2) PREP1(f.w, n + 3)
    #undef PREP1
}

// qkv bricks -> d_out attn region (free until k_sumexp overwrites it)
__global__ __launch_bounds__(256) void k_prep_qkv(
    const float* __restrict__ wq, const float* __restrict__ wk,
    const float* __restrict__ wv, float* __restrict__ attn)
{
    const int w = blockIdx.y;
    const float* W = (w == 0) ? wq : (w == 1) ? wk : wv;
    _Float16* base = (_Float16*)attn + (size_t)w * 524288;
    prep_one(W, base, base + 262144, blockIdx.x * 256 + threadIdx.x);
}

// wo bricks -> ws VH region (dead after k_pv); launched between k_pv and k_out
__global__ __launch_bounds__(256) void k_prep_wo(
    const float* __restrict__ wo, float* __restrict__ ws)
{
    _Float16* base = (_Float16*)(ws + OFF_VH);
    prep_one(wo, base, base + 262144, blockIdx.x * 256 + threadIdx.x);
}

// ---------------- QKV projection via fp16-split MFMA: X@W+b -> split heads
// 128x64 block tile, 4 waves, each wave 32m x 64n = 2x4 D-tiles of 16x16.
// No LDS, no barriers. Bricks read from d_out attn region.
__global__ __launch_bounds__(256, 3) void k_proj(
    const float* __restrict__ q, const float* __restrict__ k, const float* __restrict__ v,
    const float* __restrict__ bq, const float* __restrict__ bk, const float* __restrict__ bv,
    float* __restrict__ ws, const float* __restrict__ attn)
{
    const float *X, *bias; float* out; int wsel;
    if (blockIdx.z == 0)      { X=q; bias=bq; out=ws+OFF_QH; wsel=0; }
    else if (blockIdx.z == 1) { X=k; bias=bk; out=ws+OFF_KH; wsel=1; }
    else                      { X=v; bias=bv; out=ws+OFF_VH; wsel=2; }

    const int f = blockIdx.x + (blockIdx.y << 3);       // 0..255
    const int n0 = (f >> 5) * 64, m0 = (f & 31) * 128;  // n0<=448, m0<=3968
    const int tid = threadIdx.x, l = tid & 63, w = tid >> 6;
    const int lr = l & 15, lg = l >> 4;

    const _Float16* whi = (const _Float16*)attn + (size_t)wsel * 524288;
    const _Float16* wlo = whi + 262144;
    const float* ap0 = X + (size_t)(m0 + w*32 + lr) * DM + lg*8;
    const float* ap1 = ap0 + (size_t)16 * DM;
    const _Float16* bh_base = whi + (size_t)(n0 >> 4) * 8192 + lg*128 + lr*8;
    const _Float16* bl_base = wlo + (size_t)(n0 >> 4) * 8192 + lg*128 + lr*8;

    f32x4v aH00 = 0, aH01 = 0, aH02 = 0, aH03 = 0;
    f32x4v aH10 = 0, aH11 = 0, aH12 = 0, aH13 = 0;
    f32x4v aM00 = 0, aM01 = 0, aM02 = 0, aM03 = 0;
    f32x4v aM10 = 0, aM11 = 0, aM12 = 0, aM13 = 0;

    #pragma unroll 1
    for (int kb = 0; kb < DM; kb += 32) {
        h8 ah0, al0, ah1, al1;
        {
            const float4 u0 = *(const float4*)(ap0 + kb);
            const float4 u1 = *(const float4*)(ap0 + kb + 4);
            SPLIT8(u0, u1, ah0, al0);
            const float4 v0 = *(const float4*)(ap1 + kb);
            const float4 v1 = *(const float4*)(ap1 + kb + 4);
            SPLIT8(v0, v1, ah1, al1);
        }
        const int boff = kb * 16;
        const h8 bh0 = *(const h8*)(bh_base + boff);
        const h8 bh1 = *(const h8*)(bh_base + boff + 8192);
        const h8 bh2 = *(const h8*)(bh_base + boff + 16384);
        const h8 bh3 = *(const h8*)(bh_base + boff + 24576);
        const h8 bl0 = *(const h8*)(bl_base + boff);
        const h8 bl1 = *(const h8*)(bl_base + boff + 8192);
        const h8 bl2 = *(const h8*)(bl_base + boff + 16384);
        const h8 bl3 = *(const h8*)(bl_base + boff + 24576);

        MM(aH00, aM00, ah0, al0, bh0, bl0) MM(aH01, aM01, ah0, al0, bh1, bl1)
        MM(aH02, aM02, ah0, al0, bh2, bl2) MM(aH03, aM03, ah0, al0, bh3, bl3)
        MM(aH10, aM10, ah1, al1, bh0, bl0) MM(aH11, aM11, ah1, al1, bh1, bl1)
        MM(aH12, aM12, ah1, al1, bh2, bl2) MM(aH13, aM13, ah1, al1, bh3, bl3)
    }

    // epilogue: D[row=4*lg+reg][col=lr] per 16x16 tile (m89-verified layout)
    const int h = n0 >> 6;
    #define STORE_TILE(accH, accM, nt, mt) {                                 \
        const int n = n0 + (nt)*16 + lr;                                     \
        const float bsv = bias[n];                                           \
        const int d = n & 63;                                                \
        const int mbase = m0 + w*32 + (mt)*16 + lg*4;                        \
        _Pragma("unroll")                                                    \
        for (int r = 0; r < 4; ++r) {                                        \
            const int m = mbase + r;                                         \
            const int bb = m >> 10, s = m & 1023;                            \
            out[(((size_t)(bb*NH + h))*NS + s)*DEPTH + d] =                  \
                fmaf(accM[r], LO_INV, accH[r]) + bsv;                        \
        }                                                                    \
    }
    STORE_TILE(aH00, aM00, 0, 0) STORE_TILE(aH10, aM10, 0, 1)
    STORE_TILE(aH01, aM01, 1, 0) STORE_TILE(aH11, aM11, 1, 1)
    STORE_TILE(aH02, aM02, 2, 0) STORE_TILE(aH12, aM12, 2, 1)
    STORE_TILE(aH03, aM03, 3, 0) STORE_TILE(aH13, aM13, 3, 1)
    #undef STORE_TILE
}

// ---------------- S = K.Q^T (128x128 tile), e = exp(logits) -> nt-write e + partial sums
__global__ __launch_bounds__(256, 4) void k_sumexp(
    float* __restrict__ ws,
    const float* __restrict__ t_hb, const float* __restrict__ t_pi,
    const float* __restrict__ mask,
    const float* __restrict__ aug_hb, const float* __restrict__ aug_pi,
    const float* __restrict__ aug_at, const int* __restrict__ bnum,
    float* __restrict__ attn)
{
    __shared__ float Ks[32][132];   // [d][i]
    __shared__ float Qs[32][132];   // [d][j]
    __shared__ float wred[4];
    const int bh = blockIdx.z, b = bh >> 3;
    const int f = blockIdx.x + (blockIdx.y << 3);  // 0..63
    const int r = f & 7, qq = f >> 3;
    const int it = ((r & 1) << 2) | (qq & 3);
    const int jt = ((r >> 1) << 1) | (qq >> 2);
    const int i0 = it * 128, j0 = jt * 128;
    const float* kh = ws + OFF_KH + (size_t)bh*NS*DEPTH;
    const float* qh = ws + OFF_QH + (size_t)bh*NS*DEPTH;
    const int tid = threadIdx.x, tx = tid & 15, ty = tid >> 4;
    const int ar_ = tid >> 3, ac4 = tid & 7;

    float acc[8][8] = {};
    for (int d0 = 0; d0 < DEPTH; d0 += 32) {
        #pragma unroll
        for (int l = 0; l < 4; ++l) {
            const int rr = ar_ + l*32;
            const float4 fk = *(const float4*)(kh + (size_t)(i0+rr)*DEPTH + d0 + ac4*4);
            Ks[ac4*4+0][SW3(ac4*4+0, rr)]=fk.x; Ks[ac4*4+1][SW3(ac4*4+1, rr)]=fk.y;
            Ks[ac4*4+2][SW3(ac4*4+2, rr)]=fk.z; Ks[ac4*4+3][SW3(ac4*4+3, rr)]=fk.w;
            const float4 fq = *(const float4*)(qh + (size_t)(j0+rr)*DEPTH + d0 + ac4*4);
            Qs[ac4*4+0][SW3(ac4*4+0, rr)]=fq.x; Qs[ac4*4+1][SW3(ac4*4+1, rr)]=fq.y;
            Qs[ac4*4+2][SW3(ac4*4+2, rr)]=fq.z; Qs[ac4*4+3][SW3(ac4*4+3, rr)]=fq.w;
        }
        __syncthreads();
        #pragma unroll
        for (int d = 0; d < 32; ++d) {
            const float4 fa0 = *(const float4*)&Ks[d][SW3(d, ty*4)];
            const float4 fa1 = *(const float4*)&Ks[d][SW3(d, 64+ty*4)];
            const float4 fb0 = *(const float4*)&Qs[d][SW3(d, tx*4)];
            const float4 fb1 = *(const float4*)&Qs[d][SW3(d, 64+tx*4)];
            const float av[8] = {fa0.x,fa0.y,fa0.z,fa0.w,fa1.x,fa1.y,fa1.z,fa1.w};
            const float bw[8] = {fb0.x,fb0.y,fb0.z,fb0.w,fb1.x,fb1.y,fb1.z,fb1.w};
            #pragma unroll
            for (int i = 0; i < 8; ++i)
                #pragma unroll
                for (int j = 0; j < 8; ++j)
                    acc[i][j] = fmaf(av[i], bw[j], acc[i][j]);
        }
        __syncthreads();
    }

    const int bn = bnum[0];
    const float at = aug_at[bn], hb = aug_hb[bn], pi = aug_pi[bn];
    const float sc_at = 0.125f*at, m_at = -1e9f*at;
    float local = 0.f;
    #pragma unroll
    for (int i = 0; i < 8; ++i) {
        const int gi = i0 + (i>>2)*64 + ty*4 + (i&3);
        const size_t mrow = ((size_t)b*NS + gi)*NS;
        const size_t trow = (size_t)gi*NS;
        const size_t arow = ((size_t)bh*NS + gi)*NS;
        #pragma unroll
        for (int cb = 0; cb < 2; ++cb) {
            const int gj = j0 + cb*64 + tx*4;
            const float4 m4 = *(const float4*)(mask + mrow + gj);
            const float4 h4 = *(const float4*)(t_hb + trow + gj);
            const float4 p4 = *(const float4*)(t_pi + trow + gj);
            f4 e4;
            e4.x = __expf(fmaf(acc[i][cb*4+0], sc_at, fmaf(m4.x, m_at, fmaf(hb, h4.x, pi*p4.x))));
            e4.y = __expf(fmaf(acc[i][cb*4+1], sc_at, fmaf(m4.y, m_at, fmaf(hb, h4.y, pi*p4.y))));
            e4.z = __expf(fmaf(acc[i][cb*4+2], sc_at, fmaf(m4.z, m_at, fmaf(hb, h4.z, pi*p4.z))));
            e4.w = __expf(fmaf(acc[i][cb*4+3], sc_at, fmaf(m4.w, m_at, fmaf(hb, h4.w, pi*p4.w))));
            __builtin_nontemporal_store(e4, (f4*)(attn + arow + gj));
            local += (e4.x + e4.y) + (e4.z + e4.w);
        }
    }
    #pragma unroll
    for (int o = 32; o > 0; o >>= 1) local += __shfl_down(local, o);
    if ((tid & 63) == 0) wred[tid >> 6] = local;
    __syncthreads();
    if (tid == 0)
        ws[OFF_PART + bh*64 + it*8 + jt] =
            (wred[0] + wred[1]) + (wred[2] + wred[3]);
}

// ---------------- k_pv: inv-reduce + nt-read e, nt-write attn=e*inv, ctx_partial=(e*inv)@V
__global__ __launch_bounds__(256, 4) void k_pv(
    float* __restrict__ ws, float* __restrict__ attn)
{
    __shared__ float Es[64][68];    // [j][i], ESW-swizzled
    __shared__ float Vs[64][68];    // [j][d]
    __shared__ float s_inv;
    const int F = blockIdx.x + (blockIdx.y << 1) + (blockIdx.z << 5);  // 0..1023
    const int r = F & 7, s = F >> 3;
    const int bh = (r << 2) | (s & 3);
    const int w = s >> 2;
    const int i0 = (w >> 1) * 64;
    const int jh = w & 1;
    const int b = bh >> 3, h = bh & 7;
    const float* vh = ws + OFF_VH + (size_t)bh*NS*DEPTH;
    float* pctx = ws + (jh ? OFF_CTX1 : OFF_CTX0);
    const int tid = threadIdx.x, tx = tid & 15, ty = tid >> 4;
    const int er_ = tid >> 4, ec4 = tid & 15;

    if (tid < 64) {
        float vsum = ws[OFF_PART + bh*64 + tid];
        #pragma unroll
        for (int o = 32; o > 0; o >>= 1) vsum += __shfl_down(vsum, o);
        if (tid == 0) s_inv = 1.0f / vsum;
    }
    __syncthreads();
    const float inv = s_inv;

    float acc[4][4] = {};
    for (int jt = 0; jt < 8; ++jt) {
        const int j0 = jh*512 + jt*64;
        #pragma unroll
        for (int l = 0; l < 4; ++l) {
            const int rr = er_ + l*16;
            float* ap = attn + ((size_t)bh*NS + i0 + rr)*NS + j0 + ec4*4;
            f4 e4 = __builtin_nontemporal_load((const f4*)ap);
            e4 *= inv;
            __builtin_nontemporal_store(e4, (f4*)ap);
            Es[ec4*4+0][ESW(ec4*4+0, rr)] = e4.x;
            Es[ec4*4+1][ESW(ec4*4+1, rr)] = e4.y;
            Es[ec4*4+2][ESW(ec4*4+2, rr)] = e4.z;
            Es[ec4*4+3][ESW(ec4*4+3, rr)] = e4.w;
            *(float4*)&Vs[rr][ec4*4] = *(const float4*)(vh + (size_t)(j0+rr)*DEPTH + ec4*4);
        }
        __syncthreads();
        #pragma unroll
        for (int jj = 0; jj < 64; ++jj) {
            const float4 a  = *(const float4*)&Es[jj][ESW(jj, ty*4)];
            const float4 vv = *(const float4*)&Vs[jj][tx*4];
            const float av[4] = {a.x,a.y,a.z,a.w};
            const float vw[4] = {vv.x,vv.y,vv.z,vv.w};
            #pragma unroll
            for (int i = 0; i < 4; ++i)
                #pragma unroll
                for (int d = 0; d < 4; ++d)
                    acc[i][d] = fmaf(av[i], vw[d], acc[i][d]);
        }
        __syncthreads();
    }
    #pragma unroll
    for (int i = 0; i < 4; ++i) {
        const int gi = i0 + ty*4 + i;
        float4 o;
        o.x = acc[i][0]; o.y = acc[i][1]; o.z = acc[i][2]; o.w = acc[i][3];
        *(float4*)(pctx + ((size_t)b*NS + gi)*DM + h*DEPTH + tx*4) = o;
    }
}

// ---------------- out = (ctx0+ctx1) @ wo + b via fp16-split MFMA
// ctx pre-scaled by ASCALE so hi stays fp16-normal (ctx ~ 3e-5).
__global__ __launch_bounds__(256, 3) void k_out(
    const float* __restrict__ wsc, const float* __restrict__ bo,
    float* __restrict__ outp)
{
    const int f = blockIdx.x + (blockIdx.y << 3);       // 0..255 (grid MUST be (8,32))
    const int n0 = (f >> 5) * 64, m0 = (f & 31) * 128;
    const int tid = threadIdx.x, l = tid & 63, w = tid >> 6;
    const int lr = l & 15, lg = l >> 4;

    const _Float16* whi = (const _Float16*)(wsc + OFF_VH);   // wo bricks (VH dead)
    const _Float16* wlo = whi + 262144;
    const float* ap0 = wsc + OFF_CTX0 + (size_t)(m0 + w*32 + lr) * DM + lg*8;
    const float* ap1 = wsc + OFF_CTX1 + (size_t)(m0 + w*32 + lr) * DM + lg*8;
    const _Float16* bh_base = whi + (size_t)(n0 >> 4) * 8192 + lg*128 + lr*8;
    const _Float16* bl_base = wlo + (size_t)(n0 >> 4) * 8192 + lg*128 + lr*8;

    f32x4v aH00 = 0, aH01 = 0, aH02 = 0, aH03 = 0;
    f32x4v aH10 = 0, aH11 = 0, aH12 = 0, aH13 = 0;
    f32x4v aM00 = 0, aM01 = 0, aM02 = 0, aM03 = 0;
    f32x4v aM10 = 0, aM11 = 0, aM12 = 0, aM13 = 0;

    #pragma unroll 1
    for (int kb = 0; kb < DM; kb += 32) {
        h8 ah0, al0, ah1, al1;
        {
            float4 u0 = *(const float4*)(ap0 + kb);
            float4 u1 = *(const float4*)(ap0 + kb + 4);
            const float4 c0 = *(const float4*)(ap1 + kb);
            const float4 c1 = *(const float4*)(ap1 + kb + 4);
            u0.x=(u0.x+c0.x)*ASCALE; u0.y=(u0.y+c0.y)*ASCALE;
            u0.z=(u0.z+c0.z)*ASCALE; u0.w=(u0.w+c0.w)*ASCALE;
            u1.x=(u1.x+c1.x)*ASCALE; u1.y=(u1.y+c1.y)*ASCALE;
            u1.z=(u1.z+c1.z)*ASCALE; u1.w=(u1.w+c1.w)*ASCALE;
            SPLIT8(u0, u1, ah0, al0);
            float4 v0 = *(const float4*)(ap0 + (size_t)16*DM + kb);
            float4 v1 = *(const float4*)(ap0 + (size_t)16*DM + kb + 4);
            const float4 d0 = *(const float4*)(ap1 + (size_t)16*DM + kb);
            const float4 d1 = *(const float4*)(ap1 + (size_t)16*DM + kb + 4);
            v0.x=(v0.x+d0.x)*ASCALE; v0.y=(v0.y+d0.y)*ASCALE;
            v0.z=(v0.z+d0.z)*ASCALE; v0.w=(v0.w+d0.w)*ASCALE;
            v1.x=(v1.x+d1.x)*ASCALE; v1.y=(v1.y+d1.y)*ASCALE;
            v1.z=(v1.z+d1.z)*ASCALE; v1.w=(v1.w+d1.w)*ASCALE;
            SPLIT8(v0, v1, ah1, al1);
        }
        const int boff = kb * 16;
        const h8 bh0 = *(const h8*)(bh_base + boff);
        const h8 bh1 = *(const h8*)(bh_base + boff + 8192);
        const h8 bh2 = *(const h8*)(bh_base + boff + 16384);
        const h8 bh3 = *(const h8*)(bh_base + boff + 24576);
        const h8 bl0 = *(const h8*)(bl_base + boff);
        const h8 bl1 = *(const h8*)(bl_base + boff + 8192);
        const h8 bl2 = *(const h8*)(bl_base + boff + 16384);
        const h8 bl3 = *(const h8*)(bl_base + boff + 24576);

        MM(aH00, aM00, ah0, al0, bh0, bl0) MM(aH01, aM01, ah0, al0, bh1, bl1)
        MM(aH02, aM02, ah0, al0, bh2, bl2) MM(aH03, aM03, ah0, al0, bh3, bl3)
        MM(aH10, aM10, ah1, al1, bh0, bl0) MM(aH11, aM11, ah1, al1, bh1, bl1)
        MM(aH12, aM12, ah1, al1, bh2, bl2) MM(aH13, aM13, ah1, al1, bh3, bl3)
    }

    #define STORE_TILE(accH, accM, nt, mt) {                                 \
        const int n = n0 + (nt)*16 + lr;                                     \
        const float bsv = bo[n];                                             \
        const int mbase = m0 + w*32 + (mt)*16 + lg*4;                        \
        _Pragma("unroll")                                                    \
        for (int r = 0; r < 4; ++r)                                          \
            outp[(size_t)(mbase + r)*DM + n] =                               \
                fmaf(accM[r], LO_INV, accH[r]) * AUNSCALE + bsv;             \
    }
    STORE_TILE(aH00, aM00, 0, 0) STORE_TILE(aH10, aM10, 0, 1)
    STORE_TILE(aH01, aM01, 1, 0) STORE_TILE(aH11, aM11, 1, 1)
    STORE_TILE(aH02, aM02, 2, 0) STORE_TILE(aH12, aM12, 2, 1)
    STORE_TILE(aH03, aM03, 3, 0) STORE_TILE(aH13, aM13, 3, 1)
    #undef STORE_TILE
}

extern "C" void kernel_launch(void* const* d_in, const int* in_sizes, int n_in,
                              void* d_out, int out_size, void* d_ws, size_t ws_size,
                              hipStream_t stream)
{
    const float* v    = (const float*)d_in[0];
    const float* q    = (const float*)d_in[1];
    const float* k    = (const float*)d_in[2];
    const float* wq_w = (const float*)d_in[3];
    const float* wq_b = (const float*)d_in[4];
    const float* wk_w = (const float*)d_in[5];
    const float* wk_b = (const float*)d_in[6];
    const float* wv_w = (const float*)d_in[7];
    const float* wv_b = (const float*)d_in[8];
    const float* wo_w = (const float*)d_in[9];
    const float* wo_b = (const float*)d_in[10];
    const float* aug_hb = (const float*)d_in[11];
    const float* aug_pi = (const float*)d_in[12];
    const float* aug_at = (const float*)d_in[13];
    const float* t_hb   = (const float*)d_in[14];
    const float* t_pi   = (const float*)d_in[15];
    const float* mask   = (const float*)d_in[16];
    const int*   bnum   = (const int*)d_in[17];

    float* ws   = (float*)d_ws;
    float* outp = (float*)d_out;
    float* attn = (float*)d_out + (size_t)4*NS*DM;

    // 1. wq/wk/wv bricks into d_out attn region (overwritten later by k_sumexp)
    hipLaunchKernelGGL(k_prep_qkv, dim3(256, 3), dim3(256), 0, stream,
                       wq_w, wk_w, wv_w, attn);
    // 2. projections (MFMA), bricks from attn region
    hipLaunchKernelGGL(k_proj, dim3(8, 32, 3), dim3(256), 0, stream,
                       q, k, v, wq_b, wk_b, wv_b, ws, attn);
    // 3. scores + e + partial sums (overwrites attn with e)
    hipLaunchKernelGGL(k_sumexp, dim3(8, 8, 32), dim3(256), 0, stream,
                       ws, t_hb, t_pi, mask, aug_hb, aug_pi, aug_at, bnum, attn);
    // 4. PV + attn normalization (VH dead afterwards)
    hipLaunchKernelGGL(k_pv, dim3(2, 16, 32), dim3(256), 0, stream, ws, attn);
    // 5. wo bricks into the now-dead VH region
    hipLaunchKernelGGL(k_prep_wo, dim3(256, 1), dim3(256), 0, stream, wo_w, ws);
    // 6. output projection (MFMA) — grid (8,32): 256 blocks exactly (was the R8-R10 bug)
    hipLaunchKernelGGL(k_out, dim3(8, 32), dim3(256), 0, stream,
                       ws, wo_b, outp);
}

// Round 12
// 242.864 us; speedup vs baseline: 7.1429x; 1.0698x over previous
//
#include <hip/hip_runtime.h>
#include <math.h>

#define NS 1024
#define DM 512
#define NH 8
#define DEPTH 64

// ws offsets (floats). Lifetimes:
//  QH/KH: f16 hi+lo qh/kh (written by k_proj, read by k_score, dead after)
//         -> reused as CTX0/CTX1 by k_pv/k_out.
//  VH: fp32 vh (k_proj->k_pv), then wo bricks (k_prep_wo->k_out).
#define OFF_QH   0
#define OFF_KH   2097152
#define OFF_VH   4194304
#define OFF_CTX0 0
#define OFF_CTX1 2097152
#define OFF_PART 6291456

#define ESW(row, col) ((col) ^ ((((row) >> 3) & 7) << 2))   // rows 0..63 scatter

#define LO_SCALE 2048.0f
#define LO_INV   (1.0f/2048.0f)
#define F16_MIN_NORM 6.1035156e-5f
#define ASCALE   4096.0f
#define AUNSCALE (1.0f/4096.0f)

typedef float f4 __attribute__((ext_vector_type(4)));
typedef _Float16 h8 __attribute__((ext_vector_type(8)));
typedef float f32x4v __attribute__((ext_vector_type(4)));

// guarded hi + scaled lo (for small-magnitude data: weights, ctx)
#define SPLIT1(x, hi_e, lo_e) {                                          \
    const float x_ = (x);                                                \
    _Float16 t = (fabsf(x_) >= F16_MIN_NORM) ? (_Float16)x_ : (_Float16)0.f; \
    hi_e = t;                                                            \
    lo_e = (_Float16)((x_ - (float)t) * LO_SCALE);                       \
}

#define SPLIT8(u0, u1, hi, lo) {                                         \
    SPLIT1(u0.x, hi[0], lo[0]) SPLIT1(u0.y, hi[1], lo[1])                \
    SPLIT1(u0.z, hi[2], lo[2]) SPLIT1(u0.w, hi[3], lo[3])                \
    SPLIT1(u1.x, hi[4], lo[4]) SPLIT1(u1.y, hi[5], lo[5])                \
    SPLIT1(u1.z, hi[6], lo[6]) SPLIT1(u1.w, hi[7], lo[7])                \
}

// 3-MFMA scaled split product (separate accM, for LO_SCALE'd operands)
#define MM(accH, accM, a_h, a_l, b_h, b_l) {                                   \
    accH = __builtin_amdgcn_mfma_f32_16x16x32_f16(a_h, b_h, accH, 0, 0, 0);    \
    accM = __builtin_amdgcn_mfma_f32_16x16x32_f16(a_l, b_h, accM, 0, 0, 0);    \
    accM = __builtin_amdgcn_mfma_f32_16x16x32_f16(a_h, b_l, accM, 0, 0, 0);    \
}
// 3-MFMA unscaled split product (O(1) data: lo is fp16-normal, one acc)
#define MM1(acc, a_h, a_l, b_h, b_l) {                                         \
    acc = __builtin_amdgcn_mfma_f32_16x16x32_f16(a_h, b_h, acc, 0, 0, 0);      \
    acc = __builtin_amdgcn_mfma_f32_16x16x32_f16(a_l, b_h, acc, 0, 0, 0);      \
    acc = __builtin_amdgcn_mfma_f32_16x16x32_f16(a_h, b_l, acc, 0, 0, 0);      \
}

// ---- prep body: W fp32 -> fp16 hi + scaled-lo bricks (262144 halves each)
__device__ __forceinline__ void prep_one(
    const float* __restrict__ W, _Float16* __restrict__ whi,
    _Float16* __restrict__ wlo, int g)
{
    const int kk = g >> 7;
    const int n  = (g & 127) * 4;
    const float4 f = *(const float4*)(W + (size_t)kk * DM + n);
    const int gbase = (kk >> 3) * 128 + (kk & 7);
    #define PREP1(val, nn) {                                             \
        const int a_ = ((nn) >> 4) * 8192 + gbase + ((nn) & 15) * 8;     \
        _Float16 h_; _Float16 l_;                                        \
        SPLIT1(val, h_, l_)                                              \
        whi[a_] = h_; wlo[a_] = l_;                                      \
    }
    PREP1(f.x, n + 0) PREP1(f.y, n + 1) PREP1(f.z, n + 2) PREP1(f.w, n + 3)
    #undef PREP1
}

__global__ __launch_bounds__(256) void k_prep_qkv(
    const float* __restrict__ wq, const float* __restrict__ wk,
    const float* __restrict__ wv, float* __restrict__ attn)
{
    const int w = blockIdx.y;
    const float* W = (w == 0) ? wq : (w == 1) ? wk : wv;
    _Float16* base = (_Float16*)attn + (size_t)w * 524288;
    prep_one(W, base, base + 262144, blockIdx.x * 256 + threadIdx.x);
}

__global__ __launch_bounds__(256) void k_prep_wo(
    const float* __restrict__ wo, float* __restrict__ ws)
{
    _Float16* base = (_Float16*)(ws + OFF_VH);
    prep_one(wo, base, base + 262144, blockIdx.x * 256 + threadIdx.x);
}

// ---------------- QKV projection via fp16-split MFMA: X@W+b -> split heads
// q/k results written as f16 hi/lo planes [bh][s][d] (lo at +65536 halves);
// v written fp32 (k_pv consumes it).
__global__ __launch_bounds__(256, 3) void k_proj(
    const float* __restrict__ q, const float* __restrict__ k, const float* __restrict__ v,
    const float* __restrict__ bq, const float* __restrict__ bk, const float* __restrict__ bv,
    float* __restrict__ ws, const float* __restrict__ attn)
{
    const float *X, *bias; int wsel;
    if (blockIdx.z == 0)      { X=q; bias=bq; wsel=0; }
    else if (blockIdx.z == 1) { X=k; bias=bk; wsel=1; }
    else                      { X=v; bias=bv; wsel=2; }
    float* outf = ws + OFF_VH;                       // v only
    _Float16* outh = (_Float16*)(ws + (wsel == 0 ? OFF_QH : OFF_KH));  // q/k

    const int f = blockIdx.x + (blockIdx.y << 3);       // 0..255
    const int n0 = (f >> 5) * 64, m0 = (f & 31) * 128;
    const int tid = threadIdx.x, l = tid & 63, w = tid >> 6;
    const int lr = l & 15, lg = l >> 4;

    const _Float16* whi = (const _Float16*)attn + (size_t)wsel * 524288;
    const _Float16* wlo = whi + 262144;
    const float* ap0 = X + (size_t)(m0 + w*32 + lr) * DM + lg*8;
    const float* ap1 = ap0 + (size_t)16 * DM;
    const _Float16* bh_base = whi + (size_t)(n0 >> 4) * 8192 + lg*128 + lr*8;
    const _Float16* bl_base = wlo + (size_t)(n0 >> 4) * 8192 + lg*128 + lr*8;

    f32x4v aH00 = 0, aH01 = 0, aH02 = 0, aH03 = 0;
    f32x4v aH10 = 0, aH11 = 0, aH12 = 0, aH13 = 0;
    f32x4v aM00 = 0, aM01 = 0, aM02 = 0, aM03 = 0;
    f32x4v aM10 = 0, aM11 = 0, aM12 = 0, aM13 = 0;

    #pragma unroll 1
    for (int kb = 0; kb < DM; kb += 32) {
        h8 ah0, al0, ah1, al1;
        {
            const float4 u0 = *(const float4*)(ap0 + kb);
            const float4 u1 = *(const float4*)(ap0 + kb + 4);
            SPLIT8(u0, u1, ah0, al0);
            const float4 v0 = *(const float4*)(ap1 + kb);
            const float4 v1 = *(const float4*)(ap1 + kb + 4);
            SPLIT8(v0, v1, ah1, al1);
        }
        const int boff = kb * 16;
        const h8 bh0 = *(const h8*)(bh_base + boff);
        const h8 bh1 = *(const h8*)(bh_base + boff + 8192);
        const h8 bh2 = *(const h8*)(bh_base + boff + 16384);
        const h8 bh3 = *(const h8*)(bh_base + boff + 24576);
        const h8 bl0 = *(const h8*)(bl_base + boff);
        const h8 bl1 = *(const h8*)(bl_base + boff + 8192);
        const h8 bl2 = *(const h8*)(bl_base + boff + 16384);
        const h8 bl3 = *(const h8*)(bl_base + boff + 24576);

        MM(aH00, aM00, ah0, al0, bh0, bl0) MM(aH01, aM01, ah0, al0, bh1, bl1)
        MM(aH02, aM02, ah0, al0, bh2, bl2) MM(aH03, aM03, ah0, al0, bh3, bl3)
        MM(aH10, aM10, ah1, al1, bh0, bl0) MM(aH11, aM11, ah1, al1, bh1, bl1)
        MM(aH12, aM12, ah1, al1, bh2, bl2) MM(aH13, aM13, ah1, al1, bh3, bl3)
    }

    const int h = n0 >> 6;
    #define STORE_TILE(accH, accM, nt, mt) {                                 \
        const int n = n0 + (nt)*16 + lr;                                     \
        const float bsv = bias[n];                                           \
        const int d = n & 63;                                                \
        const int mbase = m0 + w*32 + (mt)*16 + lg*4;                        \
        _Pragma("unroll")                                                    \
        for (int r = 0; r < 4; ++r) {                                        \
            const int m = mbase + r;                                         \
            const int bb = m >> 10, s = m & 1023;                            \
            const float val = fmaf(accM[r], LO_INV, accH[r]) + bsv;          \
            if (wsel == 2) {                                                 \
                outf[(((size_t)(bb*NH + h))*NS + s)*DEPTH + d] = val;        \
            } else {                                                         \
                _Float16* p = outh + (size_t)(bb*NH + h)*131072              \
                                   + (size_t)s*64 + d;                       \
                const _Float16 hi_ = (_Float16)val;                          \
                p[0]     = hi_;                                              \
                p[65536] = (_Float16)(val - (float)hi_);                     \
            }                                                                \
        }                                                                    \
    }
    STORE_TILE(aH00, aM00, 0, 0) STORE_TILE(aH10, aM10, 0, 1)
    STORE_TILE(aH01, aM01, 1, 0) STORE_TILE(aH11, aM11, 1, 1)
    STORE_TILE(aH02, aM02, 2, 0) STORE_TILE(aH12, aM12, 2, 1)
    STORE_TILE(aH03, aM03, 3, 0) STORE_TILE(aH13, aM13, 3, 1)
    #undef STORE_TILE
}

// ---------------- k_score: S = K.Q^T via MFMA, e = exp(logits) -> nt-write e + partial sums
// 128x128 tile, 4 waves x (32i x 128j), no LDS, no K-loop barriers.
__global__ __launch_bounds__(256, 3) void k_score(
    float* __restrict__ ws,
    const float* __restrict__ t_hb, const float* __restrict__ t_pi,
    const float* __restrict__ mask,
    const float* __restrict__ aug_hb, const float* __restrict__ aug_pi,
    const float* __restrict__ aug_at, const int* __restrict__ bnum,
    float* __restrict__ attn)
{
    __shared__ float wred[4];
    const int bh = blockIdx.z, b = bh >> 3;
    const int f = blockIdx.x + (blockIdx.y << 3);  // 0..63, rect XCD grouping
    const int r = f & 7, qq = f >> 3;
    const int it = ((r & 1) << 2) | (qq & 3);
    const int jt_ = ((r >> 1) << 1) | (qq >> 2);
    const int i0 = it * 128, j0 = jt_ * 128;
    const _Float16* kb_ = (const _Float16*)(ws + OFF_KH) + (size_t)bh * 131072;
    const _Float16* qb_ = (const _Float16*)(ws + OFF_QH) + (size_t)bh * 131072;
    const int tid = threadIdx.x, l = tid & 63, w = tid >> 6;
    const int lr = l & 15, lg = l >> 4;

    // wave w covers i-rows [i0 + w*32, +32) x all 128 j
    const _Float16* ka = kb_ + (size_t)(i0 + w*32 + lr) * 64 + lg*8;
    const _Float16* qa = qb_ + (size_t)(j0 + lr) * 64 + lg*8;

    f32x4v acc[2][8] = {};
    #pragma unroll
    for (int d0 = 0; d0 < 2; ++d0) {
        const int dd = d0 * 32;
        const h8 ah0 = *(const h8*)(ka + dd);
        const h8 al0 = *(const h8*)(ka + dd + 65536);
        const h8 ah1 = *(const h8*)(ka + dd + 16*64);
        const h8 al1 = *(const h8*)(ka + dd + 16*64 + 65536);
        #pragma unroll
        for (int jt = 0; jt < 8; ++jt) {
            const h8 bhf = *(const h8*)(qa + dd + jt*16*64);
            const h8 blf = *(const h8*)(qa + dd + jt*16*64 + 65536);
            MM1(acc[0][jt], ah0, al0, bhf, blf)
            MM1(acc[1][jt], ah1, al1, bhf, blf)
        }
    }

    const int bn = bnum[0];
    const float at = aug_at[bn], hb = aug_hb[bn], pi = aug_pi[bn];
    const float sc_at = 0.125f*at, m_at = -1e9f*at;
    float local = 0.f;
    #pragma unroll
    for (int it2 = 0; it2 < 2; ++it2) {
        #pragma unroll
        for (int rr = 0; rr < 4; ++rr) {
            const int gi = i0 + w*32 + it2*16 + lg*4 + rr;
            const size_t mrow = ((size_t)b*NS + gi)*NS;
            const size_t trow = (size_t)gi*NS;
            const size_t arow = ((size_t)bh*NS + gi)*NS;
            #pragma unroll
            for (int jt = 0; jt < 8; ++jt) {
                const int gj = j0 + jt*16 + lr;
                const float mv = mask[mrow + gj];
                const float th = t_hb[trow + gj];
                const float tp = t_pi[trow + gj];
                const float e = __expf(fmaf(acc[it2][jt][rr], sc_at,
                                       fmaf(mv, m_at, fmaf(hb, th, pi*tp))));
                __builtin_nontemporal_store(e, attn + arow + gj);
                local += e;
            }
        }
    }
    #pragma unroll
    for (int o = 32; o > 0; o >>= 1) local += __shfl_down(local, o);
    if ((tid & 63) == 0) wred[tid >> 6] = local;
    __syncthreads();
    if (tid == 0)
        ws[OFF_PART + bh*64 + it*8 + jt_] =
            (wred[0] + wred[1]) + (wred[2] + wred[3]);
}

// ---------------- k_pv: inv-reduce + nt-read e, nt-write attn=e*inv, ctx_partial=(e*inv)@V
__global__ __launch_bounds__(256, 4) void k_pv(
    float* __restrict__ ws, float* __restrict__ attn)
{
    __shared__ float Es[64][68];    // [j][i], ESW-swizzled
    __shared__ float Vs[64][68];    // [j][d]
    __shared__ float s_inv;
    const int F = blockIdx.x + (blockIdx.y << 1) + (blockIdx.z << 5);  // 0..1023
    const int r = F & 7, s = F >> 3;
    const int bh = (r << 2) | (s & 3);
    const int w = s >> 2;
    const int i0 = (w >> 1) * 64;
    const int jh = w & 1;
    const int b = bh >> 3, h = bh & 7;
    const float* vh = ws + OFF_VH + (size_t)bh*NS*DEPTH;
    float* pctx = ws + (jh ? OFF_CTX1 : OFF_CTX0);
    const int tid = threadIdx.x, tx = tid & 15, ty = tid >> 4;
    const int er_ = tid >> 4, ec4 = tid & 15;

    if (tid < 64) {
        float vsum = ws[OFF_PART + bh*64 + tid];
        #pragma unroll
        for (int o = 32; o > 0; o >>= 1) vsum += __shfl_down(vsum, o);
        if (tid == 0) s_inv = 1.0f / vsum;
    }
    __syncthreads();
    const float inv = s_inv;

    float acc[4][4] = {};
    for (int jt = 0; jt < 8; ++jt) {
        const int j0 = jh*512 + jt*64;
        #pragma unroll
        for (int l = 0; l < 4; ++l) {
            const int rr = er_ + l*16;
            float* ap = attn + ((size_t)bh*NS + i0 + rr)*NS + j0 + ec4*4;
            f4 e4 = __builtin_nontemporal_load((const f4*)ap);
            e4 *= inv;
            __builtin_nontemporal_store(e4, (f4*)ap);
            Es[ec4*4+0][ESW(ec4*4+0, rr)] = e4.x;
            Es[ec4*4+1][ESW(ec4*4+1, rr)] = e4.y;
            Es[ec4*4+2][ESW(ec4*4+2, rr)] = e4.z;
            Es[ec4*4+3][ESW(ec4*4+3, rr)] = e4.w;
            *(float4*)&Vs[rr][ec4*4] = *(const float4*)(vh + (size_t)(j0+rr)*DEPTH + ec4*4);
        }
        __syncthreads();
        #pragma unroll
        for (int jj = 0; jj < 64; ++jj) {
            const float4 a  = *(const float4*)&Es[jj][ESW(jj, ty*4)];
            const float4 vv = *(const float4*)&Vs[jj][tx*4];
            const float av[4] = {a.x,a.y,a.z,a.w};
            const float vw[4] = {vv.x,vv.y,vv.z,vv.w};
            #pragma unroll
            for (int i = 0; i < 4; ++i)
                #pragma unroll
                for (int d = 0; d < 4; ++d)
                    acc[i][d] = fmaf(av[i], vw[d], acc[i][d]);
        }
        __syncthreads();
    }
    #pragma unroll
    for (int i = 0; i < 4; ++i) {
        const int gi = i0 + ty*4 + i;
        float4 o;
        o.x = acc[i][0]; o.y = acc[i][1]; o.z = acc[i][2]; o.w = acc[i][3];
        *(float4*)(pctx + ((size_t)b*NS + gi)*DM + h*DEPTH + tx*4) = o;
    }
}

// ---------------- out = (ctx0+ctx1) @ wo + b via fp16-split MFMA (ctx pre-scaled)
__global__ __launch_bounds__(256, 3) void k_out(
    const float* __restrict__ wsc, const float* __restrict__ bo,
    float* __restrict__ outp)
{
    const int f = blockIdx.x + (blockIdx.y << 3);       // grid MUST be (8,32)
    const int n0 = (f >> 5) * 64, m0 = (f & 31) * 128;
    const int tid = threadIdx.x, l = tid & 63, w = tid >> 6;
    const int lr = l & 15, lg = l >> 4;

    const _Float16* whi = (const _Float16*)(wsc + OFF_VH);
    const _Float16* wlo = whi + 262144;
    const float* ap0 = wsc + OFF_CTX0 + (size_t)(m0 + w*32 + lr) * DM + lg*8;
    const float* ap1 = wsc + OFF_CTX1 + (size_t)(m0 + w*32 + lr) * DM + lg*8;
    const _Float16* bh_base = whi + (size_t)(n0 >> 4) * 8192 + lg*128 + lr*8;
    const _Float16* bl_base = wlo + (size_t)(n0 >> 4) * 8192 + lg*128 + lr*8;

    f32x4v aH00 = 0, aH01 = 0, aH02 = 0, aH03 = 0;
    f32x4v aH10 = 0, aH11 = 0, aH12 = 0, aH13 = 0;
    f32x4v aM00 = 0, aM01 = 0, aM02 = 0, aM03 = 0;
    f32x4v aM10 = 0, aM11 = 0, aM12 = 0, aM13 = 0;

    #pragma unroll 1
    for (int kb = 0; kb < DM; kb += 32) {
        h8 ah0, al0, ah1, al1;
        {
            float4 u0 = *(const float4*)(ap0 + kb);
            float4 u1 = *(const float4*)(ap0 + kb + 4);
            const float4 c0 = *(const float4*)(ap1 + kb);
            const float4 c1 = *(const float4*)(ap1 + kb + 4);
            u0.x=(u0.x+c0.x)*ASCALE; u0.y=(u0.y+c0.y)*ASCALE;
            u0.z=(u0.z+c0.z)*ASCALE; u0.w=(u0.w+c0.w)*ASCALE;
            u1.x=(u1.x+c1.x)*ASCALE; u1.y=(u1.y+c1.y)*ASCALE;
            u1.z=(u1.z+c1.z)*ASCALE; u1.w=(u1.w+c1.w)*ASCALE;
            SPLIT8(u0, u1, ah0, al0);
            float4 v0 = *(const float4*)(ap0 + (size_t)16*DM + kb);
            float4 v1 = *(const float4*)(ap0 + (size_t)16*DM + kb + 4);
            const float4 d0 = *(const float4*)(ap1 + (size_t)16*DM + kb);
            const float4 d1 = *(const float4*)(ap1 + (size_t)16*DM + kb + 4);
            v0.x=(v0.x+d0.x)*ASCALE; v0.y=(v0.y+d0.y)*ASCALE;
            v0.z=(v0.z+d0.z)*ASCALE; v0.w=(v0.w+d0.w)*ASCALE;
            v1.x=(v1.x+d1.x)*ASCALE; v1.y=(v1.y+d1.y)*ASCALE;
            v1.z=(v1.z+d1.z)*ASCALE; v1.w=(v1.w+d1.w)*ASCALE;
            SPLIT8(v0, v1, ah1, al1);
        }
        const int boff = kb * 16;
        const h8 bh0 = *(const h8*)(bh_base + boff);
        const h8 bh1 = *(const h8*)(bh_base + boff + 8192);
        const h8 bh2 = *(const h8*)(bh_base + boff + 16384);
        const h8 bh3 = *(const h8*)(bh_base + boff + 24576);
        const h8 bl0 = *(const h8*)(bl_base + boff);
        const h8 bl1 = *(const h8*)(bl_base + boff + 8192);
        const h8 bl2 = *(const h8*)(bl_base + boff + 16384);
        const h8 bl3 = *(const h8*)(bl_base + boff + 24576);

        MM(aH00, aM00, ah0, al0, bh0, bl0) MM(aH01, aM01, ah0, al0, bh1, bl1)
        MM(aH02, aM02, ah0, al0, bh2, bl2) MM(aH03, aM03, ah0, al0, bh3, bl3)
        MM(aH10, aM10, ah1, al1, bh0, bl0) MM(aH11, aM11, ah1, al1, bh1, bl1)
        MM(aH12, aM12, ah1, al1, bh2, bl2) MM(aH13, aM13, ah1, al1, bh3, bl3)
    }

    #define STORE_TILE(accH, accM, nt, mt) {                                 \
        const int n = n0 + (nt)*16 + lr;                                     \
        const float bsv = bo[n];                                             \
        const int mbase = m0 + w*32 + (mt)*16 + lg*4;                        \
        _Pragma("unroll")                                                    \
        for (int r = 0; r < 4; ++r)                                          \
            outp[(size_t)(mbase + r)*DM + n] =                               \
                fmaf(accM[r], LO_INV, accH[r]) * AUNSCALE + bsv;             \
    }
    STORE_TILE(aH00, aM00, 0, 0) STORE_TILE(aH10, aM10, 0, 1)
    STORE_TILE(aH01, aM01, 1, 0) STORE_TILE(aH11, aM11, 1, 1)
    STORE_TILE(aH02, aM02, 2, 0) STORE_TILE(aH12, aM12, 2, 1)
    STORE_TILE(aH03, aM03, 3, 0) STORE_TILE(aH13, aM13, 3, 1)
    #undef STORE_TILE
}

extern "C" void kernel_launch(void* const* d_in, const int* in_sizes, int n_in,
                              void* d_out, int out_size, void* d_ws, size_t ws_size,
                              hipStream_t stream)
{
    const float* v    = (const float*)d_in[0];
    const float* q    = (const float*)d_in[1];
    const float* k    = (const float*)d_in[2];
    const float* wq_w = (const float*)d_in[3];
    const float* wq_b = (const float*)d_in[4];
    const float* wk_w = (const float*)d_in[5];
    const float* wk_b = (const float*)d_in[6];
    const float* wv_w = (const float*)d_in[7];
    const float* wv_b = (const float*)d_in[8];
    const float* wo_w = (const float*)d_in[9];
    const float* wo_b = (const float*)d_in[10];
    const float* aug_hb = (const float*)d_in[11];
    const float* aug_pi = (const float*)d_in[12];
    const float* aug_at = (const float*)d_in[13];
    const float* t_hb   = (const float*)d_in[14];
    const float* t_pi   = (const float*)d_in[15];
    const float* mask   = (const float*)d_in[16];
    const int*   bnum   = (const int*)d_in[17];

    float* ws   = (float*)d_ws;
    float* outp = (float*)d_out;
    float* attn = (float*)d_out + (size_t)4*NS*DM;

    // 1. wq/wk/wv bricks into d_out attn region (overwritten later by k_score)
    hipLaunchKernelGGL(k_prep_qkv, dim3(256, 3), dim3(256), 0, stream,
                       wq_w, wk_w, wv_w, attn);
    // 2. projections (MFMA); q/k -> f16 hi/lo planes, v -> fp32
    hipLaunchKernelGGL(k_proj, dim3(8, 32, 3), dim3(256), 0, stream,
                       q, k, v, wq_b, wk_b, wv_b, ws, attn);
    // 3. scores via MFMA + e + partial sums (overwrites attn with e)
    hipLaunchKernelGGL(k_score, dim3(8, 8, 32), dim3(256), 0, stream,
                       ws, t_hb, t_pi, mask, aug_hb, aug_pi, aug_at, bnum, attn);
    // 4. PV + attn normalization (VH dead afterwards)
    hipLaunchKernelGGL(k_pv, dim3(2, 16, 32), dim3(256), 0, stream, ws, attn);
    // 5. wo bricks into the now-dead VH region
    hipLaunchKernelGGL(k_prep_wo, dim3(256, 1), dim3(256), 0, stream, wo_w, ws);
    // 6. output projection (MFMA), grid (8,32) = 256 blocks exactly
    hipLaunchKernelGGL(k_out, dim3(8, 32), dim3(256), 0, stream,
                       ws, wo_b, outp);
}